// Round 14
// baseline (996.448 us; speedup 1.0000x reference)
//
#include <hip/hip_runtime.h>
#include <hip/hip_bf16.h>

typedef unsigned short ushort_t;
typedef short short8 __attribute__((ext_vector_type(8)));
typedef float f32x4 __attribute__((ext_vector_type(4)));

// ---------------- model constants ----------------
#define T_    2
#define B_    16
#define NPTS  1024
#define G_    64
#define M_    32
#define DM    384
#define NLAYER 12
#define DI    768
#define DS    16
#define DTR   24
#define DCONV 4
#define TB    32
#define KSPL  6      // xproj split-K factor (768 = 6 x 128)
#define OKC   4      // out_proj split-K chunks (768 = 4 x 192)
#define LOG2E 1.4426950408889634f

#if __has_builtin(__builtin_amdgcn_exp2f)
#define EXP2F(x) __builtin_amdgcn_exp2f(x)
#else
#define EXP2F(x) exp2f(x)
#endif

__device__ __forceinline__ ushort_t f2b(float x) {      // f32 -> bf16 RNE
    unsigned u = __float_as_uint(x);
    u = (u + 0x7FFF + ((u >> 16) & 1)) >> 16;
    return (ushort_t)u;
}
__device__ __forceinline__ float b2f(ushort_t h) { return __uint_as_float(((unsigned)h) << 16); }
#define BF1 0x3F80   // bf16(1.0)

// LIF pair for two columns: (t0,t1) x (colA,colB) -> packed t0 word, t1 word
#define LIF2(va0, vb0, va1, vb1, O0, O1) do { \
    float _u = (va0)*0.5f; float _s = (_u >= 0.5f) ? 1.f : 0.f; _u = (_s > 0.f) ? 0.f : _u; \
    float _u2 = _u + ((vb0) - _u)*0.5f; \
    unsigned _r0 = (_s > 0.f) ? (unsigned)BF1 : 0u; \
    unsigned _r1 = (_u2 >= 0.5f) ? (unsigned)BF1 : 0u; \
    _u = (va1)*0.5f; _s = (_u >= 0.5f) ? 1.f : 0.f; _u = (_s > 0.f) ? 0.f : _u; \
    _u2 = _u + ((vb1) - _u)*0.5f; \
    O0 = _r0 | (((_s > 0.f) ? (unsigned)BF1 : 0u) << 16); \
    O1 = _r1 | (((_u2 >= 0.5f) ? (unsigned)BF1 : 0u) << 16); \
} while (0)

// DPP cross-lane argmax/argmin step (VALU pipe, no ds_bpermute).
// ctrl: 0xB1 xor1, 0x4E xor2, 0x141 row_half_mirror, 0x140 row_mirror,
//       0x142 row_bcast15 (row r -> r+1), 0x143 row_bcast31 (lane31 -> lanes 32-63).
#define DPP_AMAX(bv, bi, CTRL) { \
    float _ov = __int_as_float(__builtin_amdgcn_update_dpp(__float_as_int(bv), __float_as_int(bv), CTRL, 0xF, 0xF, false)); \
    int   _oi = __builtin_amdgcn_update_dpp(bi, bi, CTRL, 0xF, 0xF, false); \
    bool _tk = (_ov > bv) || (_ov == bv && _oi < bi); \
    bv = _tk ? _ov : bv; bi = _tk ? _oi : bi; }
#define DPP_AMIN(bv, bi, CTRL) { \
    float _ov = __int_as_float(__builtin_amdgcn_update_dpp(__float_as_int(bv), __float_as_int(bv), CTRL, 0xF, 0xF, false)); \
    int   _oi = __builtin_amdgcn_update_dpp(bi, bi, CTRL, 0xF, 0xF, false); \
    bool _tk = (_ov < bv) || (_ov == bv && _oi < bi); \
    bv = _tk ? _ov : bv; bi = _tk ? _oi : bi; }
// DPP float add across quad lanes
#define DPP_FADD(p, CTRL) { \
    float _ov = __int_as_float(__builtin_amdgcn_update_dpp(__float_as_int(p), __float_as_int(p), CTRL, 0xF, 0xF, false)); \
    p += _ov; }

// ---------------- FPS: one wave per batch; all-DPP argmax reduce, zero ds_bpermute ----------------
__global__ __launch_bounds__(64) void fps_kernel(const float* __restrict__ xyz,
                                                 float* __restrict__ centers) {
    int b = blockIdx.x;
    const float* pts = xyz + (size_t)b * NPTS * 3;
    __shared__ float sx[NPTS], sy[NPTS], sz[NPTS];
    int t = threadIdx.x;
    for (int i = t; i < NPTS; i += 64) {
        sx[i] = pts[i*3+0]; sy[i] = pts[i*3+1]; sz[i] = pts[i*3+2];
    }
    __syncthreads();
    float px[16], py[16], pz[16], dd[16];
#pragma unroll
    for (int j = 0; j < 16; j++) {
        px[j] = sx[j*64+t]; py[j] = sy[j*64+t]; pz[j] = sz[j*64+t];
        dd[j] = 1e10f;
    }
    float lx = sx[0], ly = sy[0], lz = sz[0];
    for (int s = 0; s < G_; s++) {
        if (t == 0) {
            centers[(b*G_+s)*3+0] = lx;
            centers[(b*G_+s)*3+1] = ly;
            centers[(b*G_+s)*3+2] = lz;
        }
        float v[16]; int id[16];
#pragma unroll
        for (int j = 0; j < 16; j++) {
            float dx = px[j]-lx, dy = py[j]-ly, dz = pz[j]-lz;
            float di2 = dx*dx + dy*dy + dz*dz;
            dd[j] = fminf(dd[j], di2);
            v[j] = dd[j]; id[j] = j*64 + t;
        }
#pragma unroll
        for (int st = 8; st; st >>= 1)
#pragma unroll
            for (int j = 0; j < 8; j++) {
                if (j < st && v[j+st] > v[j]) { v[j] = v[j+st]; id[j] = id[j+st]; }
            }
        float bv = v[0]; int bi = id[0];
        DPP_AMAX(bv, bi, 0xB1);     // xor 1
        DPP_AMAX(bv, bi, 0x4E);     // xor 2
        DPP_AMAX(bv, bi, 0x141);    // row_half_mirror
        DPP_AMAX(bv, bi, 0x140);    // row_mirror -> each 16-row holds row argmax
        DPP_AMAX(bv, bi, 0x142);    // row_bcast15: fold row r into r+1
        DPP_AMAX(bv, bi, 0x143);    // row_bcast31: fold lower half into lanes 32-63
        int bu = __builtin_amdgcn_readlane(bi, 63);   // lane 63 holds global argmax
        lx = sx[bu]; ly = sy[bu]; lz = sz[bu];
    }
}

// ---------------- KNN: 4 waves/block; all-DPP argmin reduce ----------------
__global__ __launch_bounds__(256) void knn_kernel(const float* __restrict__ xyz,
                                                  const float* __restrict__ centers,
                                                  float* __restrict__ nb) {
    int tb = blockIdx.x >> 4;
    int g  = ((blockIdx.x & 15) << 2) + (threadIdx.x >> 6);
    const float* pts = xyz + (size_t)tb * NPTS * 3;
    int bb = tb & (B_-1);
    float cx = centers[(bb*G_+g)*3+0], cy = centers[(bb*G_+g)*3+1], cz = centers[(bb*G_+g)*3+2];
    float cs = cx*cx + cy*cy + cz*cz;
    __shared__ float sx[NPTS], sy[NPTS], sz[NPTS];
    int t = threadIdx.x & 63;
    for (int i = threadIdx.x; i < NPTS; i += 256) {
        sx[i] = pts[i*3+0]; sy[i] = pts[i*3+1]; sz[i] = pts[i*3+2];
    }
    __syncthreads();
    float d2[16];
#pragma unroll
    for (int j = 0; j < 16; j++) {
        int i = j*64 + t;
        float qx = sx[i], qy = sy[i], qz = sz[i];
        float ps  = qx*qx + qy*qy + qz*qz;
        float dot = cx*qx + cy*qy + cz*qz;
        d2[j] = cs + ps - 2.0f*dot;
    }
    for (int m = 0; m < M_; m++) {
        float v[16]; int id[16];
#pragma unroll
        for (int j = 0; j < 16; j++) { v[j] = d2[j]; id[j] = j*64 + t; }
#pragma unroll
        for (int st = 8; st; st >>= 1)
#pragma unroll
            for (int j = 0; j < 8; j++) {
                if (j < st && v[j+st] < v[j]) { v[j] = v[j+st]; id[j] = id[j+st]; }
            }
        float bv = v[0]; int bi = id[0];
        DPP_AMIN(bv, bi, 0xB1);
        DPP_AMIN(bv, bi, 0x4E);
        DPP_AMIN(bv, bi, 0x141);
        DPP_AMIN(bv, bi, 0x140);
        DPP_AMIN(bv, bi, 0x142);    // row_bcast15
        DPP_AMIN(bv, bi, 0x143);    // row_bcast31 -> lane 63 holds global argmin
        int bu = __builtin_amdgcn_readlane(bi, 63);
        if ((bu & 63) == t) {
            int jw = bu >> 6;
#pragma unroll
            for (int j = 0; j < 16; j++) if (j == jw) d2[j] = 1e38f;
        }
        if (t == 0) {
            size_t o = (((size_t)tb * G_ + g) * M_ + m) * 3;
            nb[o+0] = sx[bu] - cx;
            nb[o+1] = sy[bu] - cy;
            nb[o+2] = sz[bu] - cz;
        }
    }
}

// ---------------- bf16 hi/lo weight split ----------------
__global__ void wsplit3_kernel(const float* __restrict__ s0, int n0,
                               const float* __restrict__ s1, int n1,
                               const float* __restrict__ s2, int n2,
                               ushort_t* __restrict__ hi, ushort_t* __restrict__ lo) {
    int n = n0 + n1 + n2;
    for (int i = blockIdx.x*256 + threadIdx.x; i < n; i += gridDim.x*256) {
        float w = (i < n0) ? s0[i] : (i < n0+n1 ? s1[i-n0] : s2[i-n0-n1]);
        ushort_t h = f2b(w);
        hi[i] = h;
        lo[i] = f2b(w - b2f(h));
    }
}

// ---------------- MFMA GEMM, tile BMR x 64, scalar-register prefetch K-loop ----------------
// PF = prefetch depth (1 or 2). Depth-2 uses two named register sets (_a/_b) and a
// 2-unrolled K-loop with odd-count tail; loads issue 2 K-steps ahead of their ds_write.
// EPI 0: f32 out (straight rows).
// EPI 2: bf16 spikes only (row-pair), LDS-staged coalesced writes.
// EPI 3: fused in_proj: cols<768 -> in-block depthwise conv + LIF -> xs spikes (out ptr);
//        cols>=768 -> z-gate spikes scatter (sout). bias=conv bias, extra=conv weights.
// EPI 5: staged spikes (sout) + fused max-over-M(32) + LIF -> group spikes ((ushort*)out).
// EPI 6: enc4: bn + fused max-over-M(32) -> f32 tokens (out; half = group shift).
// EPI 7: split-K f32 out (straight rows): by = k-chunk of size 'half'; out += by*rows*ldo.
// EPI 8: split-K f32 partials (row-pair rows): by = cb + kc*(Cout/NB); extra_shift = #chunks.
template<int PRODS, int EPI, int BMR, int NB = 64, int PF = 1>
__global__ __launch_bounds__(256) void gemm_mfma(
    const ushort_t* __restrict__ A, const ushort_t* __restrict__ Al, int lda,
    const ushort_t* __restrict__ Bh, const ushort_t* __restrict__ Bl, int ldb,
    const float* __restrict__ bias, const float* __restrict__ bng, const float* __restrict__ bnb,
    const float* __restrict__ extra, int extra_shift,
    float* __restrict__ out, int ldo,
    ushort_t* __restrict__ sout, int ldso, int half,
    int rows, int K, int Cout)
{
    static_assert(NB == 64, "only NB=64 instantiated");
    constexpr int WN = (BMR == 128) ? 2 : 4;   // col-band waves
    constexpr int BANDN = NB / WN;             // cols per wave band
    constexpr int JF = BANDN / 16;
    constexpr int NA = (BMR*8)/256;            // 2 or 4 A-loads per thread per k-step
    constexpr int SMSZ = BMR*64 + NB*64*2 + ((PRODS == 3) ? BMR*64 : 8);
    __shared__ __align__(16) ushort_t SMEM[SMSZ];
    ushort_t* As  = SMEM;
    ushort_t* Bhs = SMEM + BMR*64;
    ushort_t* Bls = Bhs + NB*64;
    ushort_t* Als = Bls + NB*64;
    const int tid = threadIdx.x;
    const int bx = blockIdx.x;
    const int by = blockIdx.y;
    int cb = by, kc = 0;
    if constexpr (EPI == 8) {
        int nbc = Cout / NB;
        cb = by % nbc; kc = by / nbc;
    }
    const int c0 = (EPI == 7) ? 0 : cb * NB;
    const int r0  = bx * BMR;
    const int r0h = bx * (BMR/2);
    const int lane = tid & 63, w = tid >> 6;
    const int wm = w / WN, wn = w % WN;
    const int lrow = lane & 15, lkg = lane >> 4;
    const int sw = (lrow & 7) << 3;

    f32x4 acc[4][JF];
#pragma unroll
    for (int i = 0; i < 4; i++)
#pragma unroll
        for (int j = 0; j < JF; j++) acc[i][j] = (f32x4){0.f, 0.f, 0.f, 0.f};

    // ---- hoisted staging addresses as NAMED scalars (arrays/lambdas spill to scratch) ----
#define AINIT(II, LI, AP, ALP) { \
        int s_ = tid + (II)*256; int row_ = s_ >> 3, kq_ = s_ & 7; \
        LI = row_*64 + ((kq_*8) ^ ((row_ & 7) << 3)); \
        int grow_; \
        if constexpr (EPI == 0 || EPI == 6 || EPI == 7) grow_ = r0 + row_; \
        else { int q_ = row_ >> 4, wr_ = row_ & 15; grow_ = r0h + q_*8 + (wr_ & 7) + ((wr_ & 8) ? half : 0); } \
        AP = A + (size_t)grow_*lda + kq_*8; \
        if constexpr (PRODS == 3) ALP = Al + (size_t)grow_*lda + kq_*8; }
#define BINIT(II, LI, OK, PH, PL) { \
        int s_ = tid + (II)*256; int row_ = s_ >> 3, kq_ = s_ & 7; \
        LI = row_*64 + ((kq_*8) ^ ((row_ & 7) << 3)); \
        OK = (c0 + row_ < Cout); \
        int rc_ = OK ? (c0 + row_) : 0; \
        PH = Bh + (size_t)rc_*ldb + kq_*8; \
        PL = Bl + (size_t)rc_*ldb + kq_*8; }
    int ai0, ai1, ai2 = 0, ai3 = 0;
    const ushort_t *ap0, *ap1, *ap2 = nullptr, *ap3 = nullptr;
    const ushort_t *alp0 = nullptr, *alp1 = nullptr;
    AINIT(0, ai0, ap0, alp0);
    AINIT(1, ai1, ap1, alp1);
    if constexpr (NA == 4) {
        AINIT(2, ai2, ap2, alp0);   // PRODS==3 never has NA==4 in this model
        AINIT(3, ai3, ap3, alp0);
        AINIT(0, ai0, ap0, alp0);   // restore (compile-time folded, harmless)
    }
    int bi0, bi1; bool bk0, bk1;
    const ushort_t *bp0h, *bp0l, *bp1h, *bp1l;
    BINIT(0, bi0, bk0, bp0h, bp0l);
    BINIT(1, bi1, bk1, bp1h, bp1l);
#undef AINIT
#undef BINIT
    const uint4 Z4 = make_uint4(0,0,0,0);
    uint4 ra0_a = Z4, ra1_a = Z4, ra2_a = Z4, ra3_a = Z4, rl0_a = Z4, rl1_a = Z4;
    uint4 rb0h_a = Z4, rb0l_a = Z4, rb1h_a = Z4, rb1l_a = Z4;
    uint4 ra0_b = Z4, ra1_b = Z4, ra2_b = Z4, ra3_b = Z4, rl0_b = Z4, rl1_b = Z4;
    uint4 rb0h_b = Z4, rb0l_b = Z4, rb1h_b = Z4, rb1l_b = Z4;
#define LOADK(S, K0V) { \
        ra0##S = *(const uint4*)(ap0 + (K0V)); \
        ra1##S = *(const uint4*)(ap1 + (K0V)); \
        if constexpr (NA == 4) { \
            ra2##S = *(const uint4*)(ap2 + (K0V)); \
            ra3##S = *(const uint4*)(ap3 + (K0V)); \
        } \
        if constexpr (PRODS == 3) { \
            rl0##S = *(const uint4*)(alp0 + (K0V)); \
            rl1##S = *(const uint4*)(alp1 + (K0V)); \
        } \
        rb0h##S = bk0 ? *(const uint4*)(bp0h + (K0V)) : Z4; \
        rb0l##S = bk0 ? *(const uint4*)(bp0l + (K0V)) : Z4; \
        rb1h##S = bk1 ? *(const uint4*)(bp1h + (K0V)) : Z4; \
        rb1l##S = bk1 ? *(const uint4*)(bp1l + (K0V)) : Z4; }
#define STOREK(S) { \
        *(uint4*)&As[ai0] = ra0##S; \
        *(uint4*)&As[ai1] = ra1##S; \
        if constexpr (NA == 4) { \
            *(uint4*)&As[ai2] = ra2##S; \
            *(uint4*)&As[ai3] = ra3##S; \
        } \
        if constexpr (PRODS == 3) { \
            *(uint4*)&Als[ai0] = rl0##S; \
            *(uint4*)&Als[ai1] = rl1##S; \
        } \
        *(uint4*)&Bhs[bi0] = rb0h##S; \
        *(uint4*)&Bhs[bi1] = rb1h##S; \
        *(uint4*)&Bls[bi0] = rb0l##S; \
        *(uint4*)&Bls[bi1] = rb1l##S; }
#define MFMAK() { \
        _Pragma("unroll") \
        for (int kc2 = 0; kc2 < 2; kc2++) { \
            const int kb = (kc2*32 + lkg*8) ^ sw; \
            short8 af[4], bhf[JF], blf[JF]; \
            _Pragma("unroll") \
            for (int tI = 0; tI < 4; tI++) \
                af[tI]  = *(const short8*)&As [(wm*64 + tI*16 + lrow)*64 + kb]; \
            _Pragma("unroll") \
            for (int tJ = 0; tJ < JF; tJ++) { \
                bhf[tJ] = *(const short8*)&Bhs[(wn*BANDN + tJ*16 + lrow)*64 + kb]; \
                blf[tJ] = *(const short8*)&Bls[(wn*BANDN + tJ*16 + lrow)*64 + kb]; \
            } \
            _Pragma("unroll") \
            for (int i = 0; i < 4; i++) \
                _Pragma("unroll") \
                for (int j = 0; j < JF; j++) \
                    acc[i][j] = __builtin_amdgcn_mfma_f32_16x16x32_bf16(af[i], bhf[j], acc[i][j], 0, 0, 0); \
            _Pragma("unroll") \
            for (int i = 0; i < 4; i++) \
                _Pragma("unroll") \
                for (int j = 0; j < JF; j++) \
                    acc[i][j] = __builtin_amdgcn_mfma_f32_16x16x32_bf16(af[i], blf[j], acc[i][j], 0, 0, 0); \
            if constexpr (PRODS == 3) { \
                short8 alf[4]; \
                _Pragma("unroll") \
                for (int tI = 0; tI < 4; tI++) \
                    alf[tI] = *(const short8*)&Als[(wm*64 + tI*16 + lrow)*64 + kb]; \
                _Pragma("unroll") \
                for (int i = 0; i < 4; i++) \
                    _Pragma("unroll") \
                    for (int j = 0; j < JF; j++) \
                        acc[i][j] = __builtin_amdgcn_mfma_f32_16x16x32_bf16(alf[i], bhf[j], acc[i][j], 0, 0, 0); \
            } \
        } }

    const int kchu = (EPI == 8) ? (K / extra_shift) : 0;
    const int kbeg = (EPI == 7) ? by * half : ((EPI == 8) ? kc * kchu : 0);
    const int kend = (EPI == 7) ? kbeg + half : ((EPI == 8) ? kbeg + kchu : K);
    if constexpr (PF == 2) {
        int k0 = kbeg;
        LOADK(_a, k0);
        if (k0 + 64 < kend) LOADK(_b, k0 + 64);
        for (; k0 + 128 <= kend; k0 += 128) {
            __syncthreads();
            STOREK(_a);
            if (k0 + 128 < kend) LOADK(_a, k0 + 128);
            __syncthreads();
            MFMAK();
            __syncthreads();
            STOREK(_b);
            if (k0 + 192 < kend) LOADK(_b, k0 + 192);
            __syncthreads();
            MFMAK();
        }
        if (k0 < kend) {           // odd K-step count tail (set _a)
            __syncthreads();
            STOREK(_a);
            __syncthreads();
            MFMAK();
        }
    } else {
        LOADK(_a, kbeg);
        for (int k0 = kbeg; k0 < kend; k0 += 64) {
            __syncthreads();
            STOREK(_a);
            if (k0 + 64 < kend) LOADK(_a, k0 + 64);
            __syncthreads();
            MFMAK();
        }
    }
#undef LOADK
#undef STOREK
#undef MFMAK

    const float rbn = 1.0f / sqrtf(1.0f + 1e-5f);
    const int ocol0 = c0 + wn*BANDN + lrow;
    auto spike_pair = [&](float vt) -> ushort_t {
        float vp = __shfl_xor(vt, 32);
        float x0 = (lane < 32) ? vt : vp;
        float x1 = (lane < 32) ? vp : vt;
        float u  = x0 * 0.5f;
        float s0 = (u >= 0.5f) ? 1.f : 0.f;
        u = (s0 > 0.f) ? 0.f : u;
        float u2 = u + (x1 - u) * 0.5f;
        return (lane < 32) ? ((s0 > 0.f) ? BF1 : 0) : ((u2 >= 0.5f) ? BF1 : 0);
    };

    if constexpr (EPI == 0) {
#pragma unroll
        for (int j = 0; j < JF; j++) {
            int col = ocol0 + j*16;
            if (col >= Cout) continue;
            float bsc = 1.f, bsh = 0.f, bv = 0.f;
            if (bng)  { bsc = bng[col] * rbn; bsh = bnb[col]; }
            if (bias) bv = bias[col];
#pragma unroll
            for (int i = 0; i < 4; i++)
#pragma unroll
                for (int r = 0; r < 4; r++) {
                    int grow = r0 + wm*64 + i*16 + lkg*4 + r;
                    float v = acc[i][j][r];
                    if (extra) v += extra[(size_t)(grow >> extra_shift)*Cout + col];
                    v += bv;
                    if (bng) v = v*bsc + bsh;
                    out[(size_t)grow*ldo + col] = v;
                }
        }
    }

    if constexpr (EPI == 7) {
        float* op = out + (size_t)by * rows * ldo;
#pragma unroll
        for (int j = 0; j < JF; j++) {
            int col = ocol0 + j*16;
            if (col >= Cout) continue;
#pragma unroll
            for (int i = 0; i < 4; i++)
#pragma unroll
                for (int r = 0; r < 4; r++) {
                    int grow = r0 + wm*64 + i*16 + lkg*4 + r;
                    op[(size_t)grow*ldo + col] = acc[i][j][r];
                }
        }
    }

    if constexpr (EPI == 8) {
        // row-pair split-K partial store
        float* op = out + (size_t)kc * rows * ldo;
#pragma unroll
        for (int j = 0; j < JF; j++) {
            int col = ocol0 + j*16;
#pragma unroll
            for (int i = 0; i < 4; i++)
#pragma unroll
                for (int r = 0; r < 4; r++) {
                    int orow_t = wm*64 + i*16 + lkg*4 + r;
                    int q = orow_t >> 4, wr = orow_t & 15;
                    int grow = r0h + q*8 + (wr & 7) + ((wr & 8) ? half : 0);
                    op[(size_t)grow*ldo + col] = acc[i][j][r];
                }
        }
    }

    if constexpr (EPI == 6) {
        // enc4: bn + fused max-over-32-rows -> tokens (half = group shift, ldo = DM)
#pragma unroll
        for (int j = 0; j < JF; j++) {
            int col = ocol0 + j*16;
            float bsc = bng[col] * rbn, bsh = bnb[col], bv = bias[col];
            float m0 = -3.0e38f, m1 = -3.0e38f;
#pragma unroll
            for (int i = 0; i < 4; i++)
#pragma unroll
                for (int r = 0; r < 4; r++) {
                    float v = (acc[i][j][r] + bv) * bsc + bsh;
                    if (i < 2) m0 = fmaxf(m0, v); else m1 = fmaxf(m1, v);
                }
            m0 = fmaxf(m0, __shfl_xor(m0, 16)); m0 = fmaxf(m0, __shfl_xor(m0, 32));
            m1 = fmaxf(m1, __shfl_xor(m1, 16)); m1 = fmaxf(m1, __shfl_xor(m1, 32));
            int bg = (r0 >> 5) + wm*2;
            int msk = (1 << half) - 1;
            if (lkg == 0)
                out[(size_t)(bg >> half)*(G_*DM) + (size_t)(bg & msk)*ldo + col] = m0;
            else if (lkg == 1)
                out[(size_t)((bg+1) >> half)*(G_*DM) + (size_t)((bg+1) & msk)*ldo + col] = m1;
        }
    }

    if constexpr (EPI == 5) {
        // group max + LIF -> gls ((ushort*)out), from regs
#pragma unroll
        for (int j = 0; j < JF; j++) {
            int col = ocol0 + j*16;
            float bsc = bng[col] * rbn, bsh = bnb[col], bv = bias[col];
            float gm = -3.0e38f;
#pragma unroll
            for (int i = 0; i < 4; i++)
#pragma unroll
                for (int r = 0; r < 4; r++) {
                    float v = (acc[i][j][r] + bv) * bsc + bsh;
                    gm = fmaxf(gm, v);
                }
            float g2 = fmaxf(gm, __shfl_xor(gm, 16));
            ushort_t gsp = spike_pair(g2);
            ushort_t* gout = (ushort_t*)out;
            int bg = (r0h >> 5) + wm;
            int prs = half >> 5;
            if (lane < 16) gout[(size_t)bg * 256 + col] = gsp;
            else if (lane >= 32 && lane < 48) gout[(size_t)(prs + bg) * 256 + col] = gsp;
        }
    }

    if constexpr (EPI == 2 || EPI == 5) {
        // NB == 64: single-phase staging across As+Bhs+Bls = [128][64] f32
        __syncthreads();
        float* Ef = (float*)As;
#pragma unroll
        for (int j = 0; j < JF; j++) {
            int col = ocol0 + j*16;
            float bsc = 1.f, bsh = 0.f, bv = 0.f;
            if (bng) { bsc = bng[col] * rbn; bsh = bnb[col]; }
            if (bias) bv = bias[col];
#pragma unroll
            for (int i = 0; i < 4; i++)
#pragma unroll
                for (int r = 0; r < 4; r++) {
                    int o = wm*64 + i*16 + lkg*4 + r;
                    int pr = ((o >> 4) << 3) + (o & 7);
                    int tt = (o >> 3) & 1;
                    float v = acc[i][j][r];
                    if (EPI == 2 && extra) {
                        int grw = r0h + pr + (tt ? half : 0);
                        v += extra[(size_t)(grw >> extra_shift)*Cout + col];
                    }
                    v += bv;
                    if (bng) v = v*bsc + bsh;
                    int lr = tt*64 + pr;
                    int cc = wn*BANDN + j*16 + lrow;   // [0,64)
                    Ef[lr*64 + (cc ^ (((lr >> 2) & 3) << 4))] = v;
                }
        }
        __syncthreads();
        {
            int pr2 = tid >> 2, cs = tid & 3;
            int sw2 = ((pr2 >> 2) & 3) << 4;
            const float* E0 = Ef + pr2*64;
            const float* E1 = Ef + (64 + pr2)*64;
            int colg = c0 + cs*16;
            ushort_t* s0p = sout + (size_t)(r0h + pr2)*ldso + colg;
            ushort_t* s1p = s0p + (size_t)half*ldso;
#pragma unroll
            for (int h = 0; h < 4; h++) {
                int cb2 = (cs*16 + h*4) ^ sw2;
                const float* e0 = E0 + cb2;
                const float* e1 = E1 + cb2;
                unsigned oa, ob, pa, pb;
                LIF2(e0[0], e1[0], e0[1], e1[1], oa, pa);
                LIF2(e0[2], e1[2], e0[3], e1[3], ob, pb);
                *(uint2*)(s0p + h*4) = make_uint2(oa, ob);
                *(uint2*)(s1p + h*4) = make_uint2(pa, pb);
            }
        }
    }

    if constexpr (EPI == 3) {
        if (c0 >= DI) {
            // z-gate spikes: direct scatter (32B chunks per 16-lane group)
#pragma unroll
            for (int j = 0; j < JF; j++) {
                int col = ocol0 + j*16;
#pragma unroll
                for (int i = 0; i < 4; i++)
#pragma unroll
                    for (int r = 0; r < 4; r++) {
                        int orow_t = wm*64 + i*16 + lkg*4 + r;
                        int q = orow_t >> 4, wr = orow_t & 15;
                        int grow = r0h + q*8 + (wr & 7) + ((wr & 8) ? half : 0);
                        sout[(size_t)grow*ldso + col - DI] = spike_pair(acc[i][j][r]);
                    }
            }
        } else {
            // ---- fused depthwise conv (causal, DCONV=4) + LIF over staged accumulators ----
            __syncthreads();
            constexpr int GRP = 256 / NB;        // thread groups over l
            constexpr int LPT = 64 / GRP;        // l per thread
            constexpr int SWM = 3;
            float* Sme = wm ? (float*)Bls : (float*)Bhs;   // [32][NB] f32 each
            ushort_t* Asu = As;                  // [64][NB] spike staging (swizzled)
            if (lkg < 2) {                        // t0 rows
#pragma unroll
                for (int j = 0; j < JF; j++) {
                    int dloc = wn*BANDN + j*16 + lrow;
#pragma unroll
                    for (int i = 0; i < 4; i++) {
                        int lr0 = i*8 + lkg*4;
#pragma unroll
                        for (int r = 0; r < 4; r++)
                            Sme[(lr0 + r)*NB + dloc] = acc[i][j][r];
                    }
                }
            }
            __syncthreads();
            const int dloc_c = tid & (NB - 1);
            const int lb = (tid / NB) * LPT;
            const int dg = c0 + dloc_c;
            const float cw0 = extra[dg*4+0], cw1 = extra[dg*4+1];
            const float cw2 = extra[dg*4+2], cw3 = extra[dg*4+3];
            const float cbv = bias[dg];
            const float* S0f = (const float*)Bhs;
            const float* S1f = (const float*)Bls;
            auto SRD = [&](int l) -> float {
                return (l < 32) ? S0f[l*NB + dloc_c] : S1f[(l - 32)*NB + dloc_c];
            };
            float a0[LPT];                        // reset potential after t0
            {
                float vm3 = 0.f, vm2 = 0.f, vm1 = 0.f;
                if (lb) { vm3 = SRD(lb-3); vm2 = SRD(lb-2); vm1 = SRD(lb-1); }
#pragma unroll
                for (int q = 0; q < LPT; q++) {
                    float v = SRD(lb + q);
                    float aa = vm3*cw0 + vm2*cw1 + vm1*cw2 + v*cw3 + cbv;
                    vm3 = vm2; vm2 = vm1; vm1 = v;
                    float u = aa * 0.5f;
                    float sv = (u >= 0.5f) ? 1.f : 0.f;
                    a0[q] = (sv > 0.f) ? 0.f : u;
                    int l = lb + q;
                    Asu[l*NB + (dloc_c ^ (((l >> 1) & SWM) << 4))] = (sv > 0.f) ? BF1 : 0;
                }
            }
            __syncthreads();
            if (lkg >= 2) {                       // t1 rows
#pragma unroll
                for (int j = 0; j < JF; j++) {
                    int dloc = wn*BANDN + j*16 + lrow;
#pragma unroll
                    for (int i = 0; i < 4; i++) {
                        int lr0 = i*8 + (lkg - 2)*4;
#pragma unroll
                        for (int r = 0; r < 4; r++)
                            Sme[(lr0 + r)*NB + dloc] = acc[i][j][r];
                    }
                }
            }
            // t0 spike tile write-out (disjoint LDS from t1 staging)
            ushort_t* xb0 = (ushort_t*)out + (size_t)bx * G_ * DI + c0;
            constexpr int CPT = NB / 4;           // shorts per thread per row
            {
                int row = tid >> 2, cs2 = tid & 3;
                int sw2 = ((row >> 1) & SWM) << 4;
                ushort_t* xrow = xb0 + (size_t)row * DI;
#pragma unroll
                for (int kk = 0; kk < NB/64; kk++) {
                    int cb2 = cs2*CPT + kk*16;
                    int cl = cb2 ^ sw2;
                    uint4 va = *(uint4*)&Asu[row*NB + cl];
                    uint4 vb = *(uint4*)&Asu[row*NB + cl + 8];
                    *(uint4*)&xrow[cb2] = va;
                    *(uint4*)&xrow[cb2 + 8] = vb;
                }
            }
            __syncthreads();
            {
                float vm3 = 0.f, vm2 = 0.f, vm1 = 0.f;
                if (lb) { vm3 = SRD(lb-3); vm2 = SRD(lb-2); vm1 = SRD(lb-1); }
#pragma unroll
                for (int q = 0; q < LPT; q++) {
                    float v = SRD(lb + q);
                    float a1 = vm3*cw0 + vm2*cw1 + vm1*cw2 + v*cw3 + cbv;
                    vm3 = vm2; vm2 = vm1; vm1 = v;
                    float u2 = a0[q] + (a1 - a0[q]) * 0.5f;
                    int l = lb + q;
                    Asu[l*NB + (dloc_c ^ (((l >> 1) & SWM) << 4))] = (u2 >= 0.5f) ? BF1 : 0;
                }
            }
            __syncthreads();
            {
                int row = tid >> 2, cs2 = tid & 3;
                int sw2 = ((row >> 1) & SWM) << 4;
                ushort_t* xrow = xb0 + (size_t)16 * G_ * DI + (size_t)row * DI;
#pragma unroll
                for (int kk = 0; kk < NB/64; kk++) {
                    int cb2 = cs2*CPT + kk*16;
                    int cl = cb2 ^ sw2;
                    uint4 va = *(uint4*)&Asu[row*NB + cl];
                    uint4 vb = *(uint4*)&Asu[row*NB + cl + 8];
                    *(uint4*)&xrow[cb2] = va;
                    *(uint4*)&xrow[cb2 + 8] = vb;
                }
            }
        }
    }
}

// ---------------- out_proj split-K fixup: sum partials + residual RMW + LIF -> hs ----------------
__global__ __launch_bounds__(256) void opfix_kernel(
    const float* __restrict__ part,      // [OKC][2048][DM]
    float* __restrict__ residual, ushort_t* __restrict__ hs) {
    int e = blockIdx.x * 256 + threadIdx.x;
    if (e >= 1024 * (DM/4)) return;
    int r = e / (DM/4), c4 = (e % (DM/4)) * 4;
    size_t o0 = (size_t)r * DM + c4;
    size_t o1 = (size_t)(r + 1024) * DM + c4;
    float4 s0 = *(const float4*)(part + o0);
    float4 s1 = *(const float4*)(part + o1);
#pragma unroll
    for (int k = 1; k < OKC; k++) {
        float4 p0 = *(const float4*)(part + (size_t)k*2048*DM + o0);
        float4 p1 = *(const float4*)(part + (size_t)k*2048*DM + o1);
        s0.x += p0.x; s0.y += p0.y; s0.z += p0.z; s0.w += p0.w;
        s1.x += p1.x; s1.y += p1.y; s1.z += p1.z; s1.w += p1.w;
    }
    float4 rv0 = *(float4*)(residual + o0);
    float4 rv1 = *(float4*)(residual + o1);
    float t0x = s0.x+rv0.x, t0y = s0.y+rv0.y, t0z = s0.z+rv0.z, t0w = s0.w+rv0.w;
    float t1x = s1.x+rv1.x, t1y = s1.y+rv1.y, t1z = s1.z+rv1.z, t1w = s1.w+rv1.w;
    *(float4*)(residual + o0) = make_float4(t0x, t0y, t0z, t0w);
    *(float4*)(residual + o1) = make_float4(t1x, t1y, t1z, t1w);
    unsigned oa, ob, pa, pb;
    LIF2(t0x, t1x, t0y, t1y, oa, pa);
    LIF2(t0z, t1z, t0w, t1w, ob, pb);
    *(uint2*)(hs + o0) = make_uint2(oa, ob);
    *(uint2*)(hs + o1) = make_uint2(pa, pb);
}

// ---------------- f32 register-tiled GEMM (pos2 only) ----------------
#define KT 32
#define FMA_ROW(accv, s) { accv.x += b.x*(s); accv.y += b.y*(s); accv.z += b.z*(s); accv.w += b.w*(s); }
template<int RPT>
__global__ __launch_bounds__(256) void gemm_kernel(
    const float* __restrict__ A, int lda,
    const float* __restrict__ Wt, int ldw,
    const float* __restrict__ bias,
    float* __restrict__ out, int ldo,
    int rows, int K, int Cout, int act)
{
    constexpr int BM = RPT * 16;
    __shared__ __align__(16) float As[KT][BM];
    __shared__ __align__(16) float Bs[KT][64];
    const int tid = threadIdx.x;
    const int r0 = blockIdx.x * BM;
    const int c0 = blockIdx.y * 64;
    const int tx = tid & 15, ty = tid >> 4;
    const int colb = c0 + tx * 4;
    const float4 z4 = make_float4(0.f, 0.f, 0.f, 0.f);
    float4 acc0 = z4, acc1 = z4, acc2 = z4, acc3 = z4;
    for (int k0 = 0; k0 < K; k0 += KT) {
        for (int s = tid; s < BM * 8; s += 256) {
            int row = s >> 3, kq = s & 7;
            int dcol = row ^ (kq << 2);
            float4 va = z4;
            if (r0 + row < rows && (k0 + kq*4) < K)
                va = *(const float4*)(A + (size_t)(r0+row)*lda + k0 + kq*4);
            As[kq*4+0][dcol] = va.x; As[kq*4+1][dcol] = va.y;
            As[kq*4+2][dcol] = va.z; As[kq*4+3][dcol] = va.w;
        }
        for (int s = tid; s < 512; s += 256) {
            int row = s >> 3, kq = s & 7;
            int dcol = row ^ (kq << 2);
            float4 vb = z4;
            if (c0 + row < Cout && (k0 + kq*4) < K)
                vb = *(const float4*)(Wt + (size_t)(c0+row)*ldw + k0 + kq*4);
            Bs[kq*4+0][dcol] = vb.x; Bs[kq*4+1][dcol] = vb.y;
            Bs[kq*4+2][dcol] = vb.z; Bs[kq*4+3][dcol] = vb.w;
        }
        __syncthreads();
#pragma unroll 4
        for (int k = 0; k < KT; k++) {
            const int swz = ((k >> 2) & 7) << 2;
            const float4 b  = *(const float4*)&Bs[k][(tx*4) ^ swz];
            const float4 a0 = *(const float4*)&As[k][(ty*RPT) ^ swz];
            FMA_ROW(acc0, a0.x); FMA_ROW(acc1, a0.y);
            FMA_ROW(acc2, a0.z); FMA_ROW(acc3, a0.w);
        }
        __syncthreads();
    }
    if (colb >= Cout) return;
    float4 o4 = z4;
    if (bias) { o4.x = bias[colb]; o4.y = bias[colb+1]; o4.z = bias[colb+2]; o4.w = bias[colb+3]; }
    const int rbase = r0 + ty * RPT;
#define EPILOG(accv, rr) { \
    int row = rbase + (rr); \
    if (row < rows) { \
        float4 v = accv; \
        v.x += o4.x; v.y += o4.y; v.z += o4.z; v.w += o4.w; \
        *(float4*)(out + (size_t)row*ldo + colb) = v; \
    } }
    EPILOG(acc0, 0); EPILOG(acc1, 1); EPILOG(acc2, 2); EPILOG(acc3, 3);
#undef EPILOG
}

// ---------------- pos1 skinny matmul (K=3) + gelu ----------------
#define MMR 16
__global__ __launch_bounds__(256) void mm_kernel(
    const float* __restrict__ in, const float* __restrict__ Wt,
    const float* __restrict__ bias, float* __restrict__ out,
    int rows, int Cout, int act) {
    __shared__ __align__(16) float lds[MMR * 4];
    int tid = threadIdx.x;
    int r0  = blockIdx.x * MMR;
    int o   = tid & 127;
    for (int i = tid; i < MMR * 4; i += 256) {
        int rr = i >> 2, cc = i & 3;
        int row = r0 + rr;
        lds[i] = (row < rows && cc < 3) ? in[(size_t)row*3 + cc] : 0.f;
    }
    __syncthreads();
    if (tid >= 128 || o >= Cout) return;
    float w0 = Wt[o*3], w1 = Wt[o*3+1], w2 = Wt[o*3+2];
    float bv = bias ? bias[o] : 0.f;
    for (int r = 0; r < MMR; r++) {
        int row = r0 + r;
        if (row >= rows) break;
        float v = lds[r*4]*w0 + lds[r*4+1]*w1 + lds[r*4+2]*w2 + bv;
        if (act == 1) {
            float u = 0.7978845608028654f * (v + 0.044715f * v * v * v);
            v = 0.5f * v * (1.f + tanhf(u));
        }
        out[(size_t)row * 128 + o] = v;
    }
}

// ---------------- enc1 (K=3) + bn + LIF -> bf16 spikes ----------------
__global__ __launch_bounds__(256) void enc1_lif_kernel(
    const float* __restrict__ nb, const float* __restrict__ w, const float* __restrict__ bias,
    const float* __restrict__ bng, const float* __restrict__ bnb,
    ushort_t* __restrict__ f1s, int g0, int half, int bgsh) {
    int e = blockIdx.x * 256 + threadIdx.x;
    if (e >= half * 128) return;
    int r = e >> 7, col = e & 127;
    int tb = r >> bgsh, rem = r & ((1 << bgsh) - 1);
    int gl = rem >> 5, m = rem & 31;
    size_t i0 = (((size_t)tb * G_ + g0 + gl) * M_ + m) * 3;
    size_t i1 = i0 + (size_t)16 * G_ * M_ * 3;
    float w0 = w[col*3], w1 = w[col*3+1], w2 = w[col*3+2];
    float sc = bng[col] / sqrtf(1.f + 1e-5f), sh = bnb[col], bv = bias[col];
    float a0 = (nb[i0]*w0 + nb[i0+1]*w1 + nb[i0+2]*w2 + bv) * sc + sh;
    float a1 = (nb[i1]*w0 + nb[i1+1]*w1 + nb[i1+2]*w2 + bv) * sc + sh;
    float u  = a0 * 0.5f;
    float s0 = (u >= 0.5f) ? 1.f : 0.f;
    u = (s0 > 0.f) ? 0.f : u;
    float u2 = u + (a1 - u) * 0.5f;
    f1s[(size_t)r * 128 + col] = (s0 > 0.f) ? BF1 : 0;
    f1s[((size_t)half + r) * 128 + col] = (u2 >= 0.5f) ? BF1 : 0;
}

// ---------------- addpos + LIF -> residual f32 + hs spikes ----------------
__global__ __launch_bounds__(256) void addpos_lif_kernel(
    const float* __restrict__ tokens, const float* __restrict__ pos,
    float* __restrict__ residual, ushort_t* __restrict__ hs, int half) {
    int e = blockIdx.x * 256 + threadIdx.x;
    if (e >= half) return;
    float p = pos[e];
    float r0 = tokens[e] + p;
    float r1 = tokens[e + half] + p;
    residual[e] = r0; residual[e + half] = r1;
    float v  = r0 * 0.5f;
    float s0 = (v >= 0.5f) ? 1.f : 0.f;
    v = (s0 > 0.f) ? 0.f : v;
    float v2 = v + (r1 - v) * 0.5f;
    hs[e] = (s0 > 0.f) ? BF1 : 0;
    hs[e + half] = (v2 >= 0.5f) ? BF1 : 0;
}

// ---------------- selective scan: 4 states/lane, 64 d/block, zero global ops in loop ----------------
__global__ __launch_bounds__(256) void scan_kernel(
    const float* __restrict__ dbl,
    const ushort_t* __restrict__ xs, const ushort_t* __restrict__ zs,
    const float* __restrict__ A_log, const float* __restrict__ Dp,
    const float* __restrict__ dt_w, const float* __restrict__ dt_b,
    ushort_t* __restrict__ yh, ushort_t* __restrict__ yl) {
    int tb = blockIdx.x;
    int d0 = blockIdx.y * 64;
    int tid = threadIdx.x;
    const int dl = tid >> 2;        // local d channel 0..63
    const int sg = tid & 3;         // state group (4 states each)
    const int d  = d0 + dl;
    __shared__ float SD[G_][56];    // [dt_in(24) | B(16) | C(16)] rows
    __shared__ float SDT[G_][64];   // softplus(dt) per (l, d_local)
    __shared__ ushort_t SX[G_][64]; // xs tile
    __shared__ ushort_t SZ[G_][64]; // zs tile
    __shared__ ushort_t SYH[G_][64];// yh out tile
    __shared__ ushort_t SYL[G_][64];// yl out tile
    for (int i = tid; i < G_ * 56; i += 256) {
        int l = i / 56, j = i - l * 56;
        const float* dp0 = dbl + ((size_t)tb * G_ + l) * 56 + j;
        float sv = 0.f;
#pragma unroll
        for (int p = 0; p < KSPL; p++) sv += dp0[(size_t)p * TB * G_ * 56];
        SD[l][j] = sv;
    }
    for (int i = tid; i < G_ * 8; i += 256) {
        int row = i >> 3, seg = i & 7;
        size_t go = ((size_t)tb * G_ + row) * DI + d0 + seg*8;
        *(uint4*)&SX[row][seg*8] = *(const uint4*)(xs + go);
        *(uint4*)&SZ[row][seg*8] = *(const uint4*)(zs + go);
    }
    __syncthreads();
    {
        int dloc = tid & 63;
        int dd = d0 + dloc;
        float wdt[DTR];
#pragma unroll
        for (int k = 0; k < DTR; k++) wdt[k] = dt_w[dd * DTR + k];
        float db = dt_b[dd];
        int lbase = tid >> 6;
#pragma unroll
        for (int st = 0; st < 16; st++) {
            int l = lbase + st * 4;
            float dtv = db;
#pragma unroll
            for (int k = 0; k < DTR; k++) dtv += SD[l][k] * wdt[k];
            dtv = fmaxf(dtv, 0.f) + log1pf(EXP2F(-fabsf(dtv) * LOG2E));
            SDT[l][dloc] = dtv;
        }
    }
    __syncthreads();
    float A2[4];
#pragma unroll
    for (int k = 0; k < 4; k++)
        A2[k] = -EXP2F(A_log[d * DS + 4*sg + k] * LOG2E) * LOG2E;
    const float dpv = Dp[d];
    float h0 = 0.f, h1 = 0.f, h2 = 0.f, h3 = 0.f;
#pragma unroll 4
    for (int l = 0; l < G_; l++) {
        float dtv = SDT[l][dl];
        float4 Bv = *(const float4*)&SD[l][DTR + 4*sg];
        float4 Cv = *(const float4*)&SD[l][DTR + DS + 4*sg];
        float xv = b2f(SX[l][dl]);
        float dx = dtv * xv;
        h0 = h0 * EXP2F(dtv * A2[0]) + dx * Bv.x;
        h1 = h1 * EXP2F(dtv * A2[1]) + dx * Bv.y;
        h2 = h2 * EXP2F(dtv * A2[2]) + dx * Bv.z;
        h3 = h3 * EXP2F(dtv * A2[3]) + dx * Bv.w;
        float p = h0*Cv.x + h1*Cv.y + h2*Cv.z + h3*Cv.w;
        DPP_FADD(p, 0xB1);          // += lane^1 (quad_perm, VALU)
        DPP_FADD(p, 0x4E);          // += lane^2
        if (sg == 0) {
            float y = (p + xv * dpv) * b2f(SZ[l][dl]);
            ushort_t hb = f2b(y);
            SYH[l][dl] = hb;
            SYL[l][dl] = f2b(y - b2f(hb));
        }
    }
    __syncthreads();
    for (int i = tid; i < G_ * 8; i += 256) {
        int row = i >> 3, seg = i & 7;
        size_t go = ((size_t)tb * G_ + row) * DI + d0 + seg*8;
        *(uint4*)(yh + go) = *(uint4*)&SYH[row][seg*8];
        *(uint4*)(yl + go) = *(uint4*)&SYL[row][seg*8];
    }
}

// ---------------- final LayerNorm (single input) ----------------
__global__ __launch_bounds__(128) void ln_kernel(const float* __restrict__ in1,
                                                 const float* __restrict__ g,
                                                 const float* __restrict__ b,
                                                 float* __restrict__ out) {
    int row = blockIdx.x;
    __shared__ float xsm[DM];
    __shared__ float red[128];
    int tid = threadIdx.x;
    float s = 0.f;
    for (int c = tid; c < DM; c += 128) {
        float x = in1[(size_t)row * DM + c];
        xsm[c] = x; s += x;
    }
    red[tid] = s; __syncthreads();
    for (int w = 64; w > 0; w >>= 1) { if (tid < w) red[tid] += red[tid + w]; __syncthreads(); }
    float mu = red[0] / DM;
    __syncthreads();
    float s2 = 0.f;
    for (int c = tid; c < DM; c += 128) { float dv = xsm[c] - mu; s2 += dv * dv; }
    red[tid] = s2; __syncthreads();
    for (int w = 64; w > 0; w >>= 1) { if (tid < w) red[tid] += red[tid + w]; __syncthreads(); }
    float var = red[0] / DM;
    float inv = 1.f / sqrtf(var + 1e-5f);
    for (int c = tid; c < DM; c += 128)
        out[(size_t)row * DM + c] = (xsm[c] - mu) * inv * g[c] + b[c];
}

// ---------------- host orchestration ----------------
extern "C" void kernel_launch(void* const* d_in, const int* in_sizes, int n_in,
                              void* d_out, int out_size, void* d_ws, size_t ws_size,
                              hipStream_t stream) {
    const float* xyz     = (const float*)d_in[0];
    const float* enc1_w  = (const float*)d_in[1];  const float* enc1_b = (const float*)d_in[2];
    const float* bn1_g   = (const float*)d_in[3];  const float* bn1_b  = (const float*)d_in[4];
    const float* enc2_w  = (const float*)d_in[5];  const float* enc2_b = (const float*)d_in[6];
    const float* bn2_g   = (const float*)d_in[7];  const float* bn2_b  = (const float*)d_in[8];
    const float* enc3_w  = (const float*)d_in[9];  const float* enc3_b = (const float*)d_in[10];
    const float* bn3_g   = (const float*)d_in[11]; const float* bn3_b  = (const float*)d_in[12];
    const float* enc4_w  = (const float*)d_in[13]; const float* enc4_b = (const float*)d_in[14];
    const float* bn4_g   = (const float*)d_in[15]; const float* bn4_b  = (const float*)d_in[16];
    const float* pos1_w  = (const float*)d_in[17]; const float* pos1_b = (const float*)d_in[18];
    const float* pos2_w  = (const float*)d_in[19]; const float* pos2_b = (const float*)d_in[20];
    const float* in_w    = (const float*)d_in[21];
    const float* conv_w  = (const float*)d_in[22]; const float* conv_b = (const float*)d_in[23];
    const float* xproj_w = (const float*)d_in[24];
    const float* dt_w    = (const float*)d_in[25]; const float* dt_b   = (const float*)d_in[26];
    const float* A_log   = (const float*)d_in[27]; const float* Dp     = (const float*)d_in[28];
    const float* out_w   = (const float*)d_in[29];
    const float* normf_g = (const float*)d_in[30]; const float* normf_b = (const float*)d_in[31];
    float* outp = (float*)d_out;
    float* ws   = (float*)d_ws;
    const size_t wf = ws_size / 4;

    // ---- plan selection: widest encoder chunk that fits ----
    const size_t NIW = 12*589824, NXP = 12*43008, NOW = 12*294912;
    auto pool_need = [&](int g) -> size_t {
        size_t R = (size_t)g*1024, CBx = (size_t)g*32;
        return R*1088 + CBx*640;
    };
    const size_t fixed_need = 4200000;
    int gch = 8; bool split_all = false;
    {
        const int cand[4] = {64, 32, 16, 8};
        for (int ci = 0; ci < 4; ci++) {
            if (fixed_need + (NIW+NXP+NOW) + pool_need(cand[ci]) <= wf) {
                gch = cand[ci]; split_all = true; break;
            }
        }
    }
    auto ilog2i = [](int x){ int r = 0; while ((1 << r) < x) r++; return r; };
    const int R = gch*1024, HALF = R/2, CB = gch*32;
    const int NCH = 64/gch;
    const int BGSH = 5 + ilog2i(gch);
    const int OGSH = ilog2i(gch);

    size_t off = 0;
    auto alloc = [&](size_t n) { off = (off + 15) & ~(size_t)15; float* p = ws + off; off += n; return p; };
    float* centers  = alloc(3072);
    float* nb       = alloc(196608);
    float* tokens   = alloc(786432);
    float* post     = alloc(131072);
    float* pos      = alloc(393216);
    float* residual = alloc(786432);
    ushort_t* hs_b  = (ushort_t*)alloc(393216);
    ushort_t* ewhi  = (ushort_t*)alloc(245760);
    ushort_t* ewlo  = (ushort_t*)alloc(245760);
    size_t wsz = split_all ? (NIW+NXP+NOW) : 927744;
    ushort_t* whi = (ushort_t*)alloc((wsz+1)/2);
    ushort_t* wlo = (ushort_t*)alloc((wsz+1)/2);
    float* pool = alloc(pool_need(gch));
    // encoder aliases
    float* f2 = pool;
    float* f4 = f2 + (size_t)R*256;
    float* g3 = f4 + (size_t)R*384;
    ushort_t* f1s = (ushort_t*)(g3 + (size_t)CB*512);
    ushort_t* f2s = f1s + (size_t)R*128;
    ushort_t* f3s = f2s + (size_t)R*256;
    ushort_t* gls = f3s + (size_t)R*512;
    // mamba aliases (encoder done before use); dblb holds KSPL split-K partials
    float* dblb  = pool;                                   // KSPL * 2048 * 56
    ushort_t* xs_b = (ushort_t*)(dblb + KSPL * TB * G_ * 56);
    ushort_t* zs_b = xs_b + 1572864;
    ushort_t* ysh  = zs_b + 1572864;
    ushort_t* ysl  = ysh + 1572864;
    float* opart   = (float*)(ysl + 1572864);              // OKC * 2048 * DM f32

    // weight splits
    wsplit3_kernel<<<512, 256, 0, stream>>>(enc2_w, 32768, enc3_w, 262144, enc4_w, 196608, ewhi, ewlo);
    const int E2 = 0, E3 = 32768, E4 = 294912;
    if (split_all)
        wsplit3_kernel<<<2048, 256, 0, stream>>>(in_w, (int)NIW, xproj_w, (int)NXP, out_w, (int)NOW, whi, wlo);

    fps_kernel<<<B_, 64, 0, stream>>>(xyz, centers);
    knn_kernel<<<TB * 16, 256, 0, stream>>>(xyz, centers, nb);

    // ---- encoder ----
    for (int ch = 0; ch < NCH; ch++) {
        int g0 = ch * gch;
        enc1_lif_kernel<<<(HALF*128 + 255)/256, 256, 0, stream>>>(
            nb, enc1_w, enc1_b, bn1_g, bn1_b, f1s, g0, HALF, BGSH);
        // enc2 + bn + staged spikes + fused max-over-M + LIF -> gls
        gemm_mfma<2,5,128,64><<<dim3(HALF/64, 4), 256, 0, stream>>>(
            f1s, nullptr, 128, ewhi + E2, ewlo + E2, 128,
            enc2_b, bn2_g, bn2_b, nullptr, 0, (float*)gls, 0, f2s, 256, HALF, R, 128, 256);
        gemm_mfma<2,0,64,64><<<dim3(CB/64, 8), 256, 0, stream>>>(
            gls, nullptr, 256, ewhi + E3, ewlo + E3, 512,
            nullptr, nullptr, nullptr, nullptr, 0, g3, 512, nullptr, 0, 0, CB, 256, 512);
        gemm_mfma<2,2,128,64><<<dim3(HALF/64, 8), 256, 0, stream>>>(
            f2s, nullptr, 256, ewhi + E3 + 256, ewlo + E3 + 256, 512,
            enc3_b, bn3_g, bn3_b, g3, 5, nullptr, 512, f3s, 512, HALF, R, 256, 512);
        // enc4 + bn + fused max-over-M -> tokens (no f4 round-trip)
        gemm_mfma<2,6,128,64><<<dim3(R/128, 6), 256, 0, stream>>>(
            f3s, nullptr, 512, ewhi + E4, ewlo + E4, 512,
            enc4_b, bn4_g, bn4_b, nullptr, 0,
            tokens + (size_t)g0 * DM, DM, nullptr, 0, OGSH, R, 512, 384);
    }

    // ---- positional embedding (+ layer-0 residual/LIF) ----
    mm_kernel<<<64, 256, 0, stream>>>(centers, pos1_w, pos1_b, post, 1024, 128, 1);
    gemm_kernel<4><<<dim3(16, 6), 256, 0, stream>>>(
        post, 128, pos2_w, 128, pos2_b, pos, 384, 1024, 128, 384, 0);
    addpos_lif_kernel<<<(393216 + 255) / 256, 256, 0, stream>>>(
        tokens, pos, residual, hs_b, 393216);

    // ---- 12 spiking-Mamba layers ----
    const int NTOK = TB * G_;
    for (int l = 0; l < NLAYER; l++) {
        size_t W_IN, W_XP, W_OUT;
        if (split_all) {
            W_IN = (size_t)l * 589824;
            W_XP = NIW + (size_t)l * 43008;
            W_OUT = NIW + NXP + (size_t)l * 294912;
        } else {
            wsplit3_kernel<<<1024, 256, 0, stream>>>(
                in_w + (size_t)l * 589824, 589824,
                xproj_w + (size_t)l * 43008, 43008,
                out_w + (size_t)l * 294912, 294912, whi, wlo);
            W_IN = 0; W_XP = 589824; W_OUT = 632832;
        }
        // in_proj fused with depthwise conv + LIF (xh cols) and z-gate spikes (z cols); PF=2
        gemm_mfma<2,3,128,64,2><<<dim3(NTOK/128, 24), 256, 0, stream>>>(
            hs_b, nullptr, DM, whi + W_IN, wlo + W_IN, DM,
            conv_b + (size_t)l * DI, nullptr, nullptr, conv_w + (size_t)l * DI * DCONV, 0,
            (float*)xs_b, 0, zs_b, DI, NTOK/2, NTOK, DM, 2*DI);
        // xproj: split-K over 6 chunks -> dblb partials (summed inside scan); PF=2
        gemm_mfma<2,7,64,64,2><<<dim3(NTOK/64, KSPL), 256, 0, stream>>>(
            xs_b, nullptr, DI, whi + W_XP, wlo + W_XP, DI,
            nullptr, nullptr, nullptr, nullptr, 0, dblb, 56, nullptr, 0, DI/KSPL, NTOK, DI, 56);
        // scan (fused dt_proj + gate, 4-state lanes, LDS-resident loop) -> ys hi/lo
        scan_kernel<<<dim3(TB, DI/64), 256, 0, stream>>>(
            dblb, xs_b, zs_b, A_log + (size_t)l * DI * DS, Dp + (size_t)l * DI,
            dt_w + (size_t)l * DI * DTR, dt_b + (size_t)l * DI, ysh, ysl);
        // out_proj split-K (4 chunks x 6 col bands) -> opart partials; PF=2
        gemm_mfma<3,8,64,64,2><<<dim3(NTOK/64, 6*OKC), 256, 0, stream>>>(
            ysh, ysl, DI, whi + W_OUT, wlo + W_OUT, DI,
            nullptr, nullptr, nullptr, nullptr, OKC, opart, DM, nullptr, 0, NTOK/2, NTOK, DI, DM);
        // fixup: sum partials + residual RMW + next-layer LIF spikes
        opfix_kernel<<<(1024*(DM/4) + 255)/256, 256, 0, stream>>>(opart, residual, hs_b);
    }
    ln_kernel<<<NTOK, 128, 0, stream>>>(residual, normf_g, normf_b, outp);
}

// Round 15
// 984.288 us; speedup vs baseline: 1.0124x; 1.0124x over previous
//
#include <hip/hip_runtime.h>
#include <hip/hip_bf16.h>

typedef unsigned short ushort_t;
typedef short short8 __attribute__((ext_vector_type(8)));
typedef float f32x4 __attribute__((ext_vector_type(4)));

// ---------------- model constants ----------------
#define T_    2
#define B_    16
#define NPTS  1024
#define G_    64
#define M_    32
#define DM    384
#define NLAYER 12
#define DI    768
#define DS    16
#define DTR   24
#define DCONV 4
#define TB    32
#define KSPL  6      // xproj split-K factor (768 = 6 x 128)
#define OKC   4      // out_proj split-K chunks (768 = 4 x 192)
#define LOG2E 1.4426950408889634f

#if __has_builtin(__builtin_amdgcn_exp2f)
#define EXP2F(x) __builtin_amdgcn_exp2f(x)
#else
#define EXP2F(x) exp2f(x)
#endif

__device__ __forceinline__ ushort_t f2b(float x) {      // f32 -> bf16 RNE
    unsigned u = __float_as_uint(x);
    u = (u + 0x7FFF + ((u >> 16) & 1)) >> 16;
    return (ushort_t)u;
}
__device__ __forceinline__ float b2f(ushort_t h) { return __uint_as_float(((unsigned)h) << 16); }
#define BF1 0x3F80   // bf16(1.0)

// LIF pair for two columns: (t0,t1) x (colA,colB) -> packed t0 word, t1 word
#define LIF2(va0, vb0, va1, vb1, O0, O1) do { \
    float _u = (va0)*0.5f; float _s = (_u >= 0.5f) ? 1.f : 0.f; _u = (_s > 0.f) ? 0.f : _u; \
    float _u2 = _u + ((vb0) - _u)*0.5f; \
    unsigned _r0 = (_s > 0.f) ? (unsigned)BF1 : 0u; \
    unsigned _r1 = (_u2 >= 0.5f) ? (unsigned)BF1 : 0u; \
    _u = (va1)*0.5f; _s = (_u >= 0.5f) ? 1.f : 0.f; _u = (_s > 0.f) ? 0.f : _u; \
    _u2 = _u + ((vb1) - _u)*0.5f; \
    O0 = _r0 | (((_s > 0.f) ? (unsigned)BF1 : 0u) << 16); \
    O1 = _r1 | (((_u2 >= 0.5f) ? (unsigned)BF1 : 0u) << 16); \
} while (0)

// DPP cross-lane argmax/argmin step (VALU pipe, no ds_bpermute).
// ctrl: 0xB1 xor1, 0x4E xor2, 0x141 row_half_mirror, 0x140 row_mirror,
//       0x142 row_bcast15 (row r -> r+1), 0x143 row_bcast31 (lane31 -> lanes 32-63).
#define DPP_AMAX(bv, bi, CTRL) { \
    float _ov = __int_as_float(__builtin_amdgcn_update_dpp(__float_as_int(bv), __float_as_int(bv), CTRL, 0xF, 0xF, false)); \
    int   _oi = __builtin_amdgcn_update_dpp(bi, bi, CTRL, 0xF, 0xF, false); \
    bool _tk = (_ov > bv) || (_ov == bv && _oi < bi); \
    bv = _tk ? _ov : bv; bi = _tk ? _oi : bi; }
#define DPP_AMIN(bv, bi, CTRL) { \
    float _ov = __int_as_float(__builtin_amdgcn_update_dpp(__float_as_int(bv), __float_as_int(bv), CTRL, 0xF, 0xF, false)); \
    int   _oi = __builtin_amdgcn_update_dpp(bi, bi, CTRL, 0xF, 0xF, false); \
    bool _tk = (_ov < bv) || (_ov == bv && _oi < bi); \
    bv = _tk ? _ov : bv; bi = _tk ? _oi : bi; }
// DPP float add across quad lanes
#define DPP_FADD(p, CTRL) { \
    float _ov = __int_as_float(__builtin_amdgcn_update_dpp(__float_as_int(p), __float_as_int(p), CTRL, 0xF, 0xF, false)); \
    p += _ov; }

// ---------------- FPS: one wave per batch; all-DPP argmax reduce, zero ds_bpermute ----------------
__global__ __launch_bounds__(64) void fps_kernel(const float* __restrict__ xyz,
                                                 float* __restrict__ centers) {
    int b = blockIdx.x;
    const float* pts = xyz + (size_t)b * NPTS * 3;
    __shared__ float sx[NPTS], sy[NPTS], sz[NPTS];
    int t = threadIdx.x;
    for (int i = t; i < NPTS; i += 64) {
        sx[i] = pts[i*3+0]; sy[i] = pts[i*3+1]; sz[i] = pts[i*3+2];
    }
    __syncthreads();
    float px[16], py[16], pz[16], dd[16];
#pragma unroll
    for (int j = 0; j < 16; j++) {
        px[j] = sx[j*64+t]; py[j] = sy[j*64+t]; pz[j] = sz[j*64+t];
        dd[j] = 1e10f;
    }
    float lx = sx[0], ly = sy[0], lz = sz[0];
    for (int s = 0; s < G_; s++) {
        if (t == 0) {
            centers[(b*G_+s)*3+0] = lx;
            centers[(b*G_+s)*3+1] = ly;
            centers[(b*G_+s)*3+2] = lz;
        }
        float v[16]; int id[16];
#pragma unroll
        for (int j = 0; j < 16; j++) {
            float dx = px[j]-lx, dy = py[j]-ly, dz = pz[j]-lz;
            float di2 = dx*dx + dy*dy + dz*dz;
            dd[j] = fminf(dd[j], di2);
            v[j] = dd[j]; id[j] = j*64 + t;
        }
#pragma unroll
        for (int st = 8; st; st >>= 1)
#pragma unroll
            for (int j = 0; j < 8; j++) {
                if (j < st && v[j+st] > v[j]) { v[j] = v[j+st]; id[j] = id[j+st]; }
            }
        float bv = v[0]; int bi = id[0];
        DPP_AMAX(bv, bi, 0xB1);     // xor 1
        DPP_AMAX(bv, bi, 0x4E);     // xor 2
        DPP_AMAX(bv, bi, 0x141);    // row_half_mirror
        DPP_AMAX(bv, bi, 0x140);    // row_mirror -> each 16-row holds row argmax
        DPP_AMAX(bv, bi, 0x142);    // row_bcast15: fold row r into r+1
        DPP_AMAX(bv, bi, 0x143);    // row_bcast31: fold lower half into lanes 32-63
        int bu = __builtin_amdgcn_readlane(bi, 63);   // lane 63 holds global argmax
        lx = sx[bu]; ly = sy[bu]; lz = sz[bu];
    }
}

// ---------------- KNN: 4 waves/block; all-DPP argmin reduce ----------------
__global__ __launch_bounds__(256) void knn_kernel(const float* __restrict__ xyz,
                                                  const float* __restrict__ centers,
                                                  float* __restrict__ nb) {
    int tb = blockIdx.x >> 4;
    int g  = ((blockIdx.x & 15) << 2) + (threadIdx.x >> 6);
    const float* pts = xyz + (size_t)tb * NPTS * 3;
    int bb = tb & (B_-1);
    float cx = centers[(bb*G_+g)*3+0], cy = centers[(bb*G_+g)*3+1], cz = centers[(bb*G_+g)*3+2];
    float cs = cx*cx + cy*cy + cz*cz;
    __shared__ float sx[NPTS], sy[NPTS], sz[NPTS];
    int t = threadIdx.x & 63;
    for (int i = threadIdx.x; i < NPTS; i += 256) {
        sx[i] = pts[i*3+0]; sy[i] = pts[i*3+1]; sz[i] = pts[i*3+2];
    }
    __syncthreads();
    float d2[16];
#pragma unroll
    for (int j = 0; j < 16; j++) {
        int i = j*64 + t;
        float qx = sx[i], qy = sy[i], qz = sz[i];
        float ps  = qx*qx + qy*qy + qz*qz;
        float dot = cx*qx + cy*qy + cz*qz;
        d2[j] = cs + ps - 2.0f*dot;
    }
    for (int m = 0; m < M_; m++) {
        float v[16]; int id[16];
#pragma unroll
        for (int j = 0; j < 16; j++) { v[j] = d2[j]; id[j] = j*64 + t; }
#pragma unroll
        for (int st = 8; st; st >>= 1)
#pragma unroll
            for (int j = 0; j < 8; j++) {
                if (j < st && v[j+st] < v[j]) { v[j] = v[j+st]; id[j] = id[j+st]; }
            }
        float bv = v[0]; int bi = id[0];
        DPP_AMIN(bv, bi, 0xB1);
        DPP_AMIN(bv, bi, 0x4E);
        DPP_AMIN(bv, bi, 0x141);
        DPP_AMIN(bv, bi, 0x140);
        DPP_AMIN(bv, bi, 0x142);    // row_bcast15
        DPP_AMIN(bv, bi, 0x143);    // row_bcast31 -> lane 63 holds global argmin
        int bu = __builtin_amdgcn_readlane(bi, 63);
        if ((bu & 63) == t) {
            int jw = bu >> 6;
#pragma unroll
            for (int j = 0; j < 16; j++) if (j == jw) d2[j] = 1e38f;
        }
        if (t == 0) {
            size_t o = (((size_t)tb * G_ + g) * M_ + m) * 3;
            nb[o+0] = sx[bu] - cx;
            nb[o+1] = sy[bu] - cy;
            nb[o+2] = sz[bu] - cz;
        }
    }
}

// ---------------- bf16 hi/lo weight split ----------------
__global__ void wsplit3_kernel(const float* __restrict__ s0, int n0,
                               const float* __restrict__ s1, int n1,
                               const float* __restrict__ s2, int n2,
                               ushort_t* __restrict__ hi, ushort_t* __restrict__ lo) {
    int n = n0 + n1 + n2;
    for (int i = blockIdx.x*256 + threadIdx.x; i < n; i += gridDim.x*256) {
        float w = (i < n0) ? s0[i] : (i < n0+n1 ? s1[i-n0] : s2[i-n0-n1]);
        ushort_t h = f2b(w);
        hi[i] = h;
        lo[i] = f2b(w - b2f(h));
    }
}

// ---------------- MFMA GEMM, tile BMR x 64, scalar-register prefetch K-loop (PF=1) ----------------
// EPI 0: f32 out (straight rows).
// EPI 2: bf16 spikes only (row-pair), LDS-staged coalesced writes.
// EPI 3: fused in_proj: cols<768 -> in-block depthwise conv + LIF -> xs spikes (out ptr);
//        cols>=768 -> z-gate spikes scatter (sout). bias=conv bias, extra=conv weights.
// EPI 5: staged spikes (sout) + fused max-over-M(32) + LIF -> group spikes ((ushort*)out).
// EPI 6: enc4: bn + fused max-over-M(32) -> f32 tokens (out; half = group shift).
// EPI 7: split-K f32 out (straight rows): by = k-chunk of size 'half'; out += by*rows*ldo.
// EPI 8: split-K f32 partials (row-pair rows): by = cb + kc*(Cout/NB); extra_shift = #chunks.
template<int PRODS, int EPI, int BMR, int NB = 64, int PF = 1>
__global__ __launch_bounds__(256) void gemm_mfma(
    const ushort_t* __restrict__ A, const ushort_t* __restrict__ Al, int lda,
    const ushort_t* __restrict__ Bh, const ushort_t* __restrict__ Bl, int ldb,
    const float* __restrict__ bias, const float* __restrict__ bng, const float* __restrict__ bnb,
    const float* __restrict__ extra, int extra_shift,
    float* __restrict__ out, int ldo,
    ushort_t* __restrict__ sout, int ldso, int half,
    int rows, int K, int Cout)
{
    static_assert(NB == 64, "only NB=64 instantiated");
    constexpr int WN = (BMR == 128) ? 2 : 4;   // col-band waves
    constexpr int BANDN = NB / WN;             // cols per wave band
    constexpr int JF = BANDN / 16;
    constexpr int NA = (BMR*8)/256;            // 2 or 4 A-loads per thread per k-step
    constexpr int SMSZ = BMR*64 + NB*64*2 + ((PRODS == 3) ? BMR*64 : 8);
    __shared__ __align__(16) ushort_t SMEM[SMSZ];
    ushort_t* As  = SMEM;
    ushort_t* Bhs = SMEM + BMR*64;
    ushort_t* Bls = Bhs + NB*64;
    ushort_t* Als = Bls + NB*64;
    const int tid = threadIdx.x;
    const int bx = blockIdx.x;
    const int by = blockIdx.y;
    int cb = by, kc = 0;
    if constexpr (EPI == 8) {
        int nbc = Cout / NB;
        cb = by % nbc; kc = by / nbc;
    }
    const int c0 = (EPI == 7) ? 0 : cb * NB;
    const int r0  = bx * BMR;
    const int r0h = bx * (BMR/2);
    const int lane = tid & 63, w = tid >> 6;
    const int wm = w / WN, wn = w % WN;
    const int lrow = lane & 15, lkg = lane >> 4;
    const int sw = (lrow & 7) << 3;

    f32x4 acc[4][JF];
#pragma unroll
    for (int i = 0; i < 4; i++)
#pragma unroll
        for (int j = 0; j < JF; j++) acc[i][j] = (f32x4){0.f, 0.f, 0.f, 0.f};

    // ---- hoisted staging addresses as NAMED scalars (arrays/lambdas spill to scratch) ----
#define AINIT(II, LI, AP, ALP) { \
        int s_ = tid + (II)*256; int row_ = s_ >> 3, kq_ = s_ & 7; \
        LI = row_*64 + ((kq_*8) ^ ((row_ & 7) << 3)); \
        int grow_; \
        if constexpr (EPI == 0 || EPI == 6 || EPI == 7) grow_ = r0 + row_; \
        else { int q_ = row_ >> 4, wr_ = row_ & 15; grow_ = r0h + q_*8 + (wr_ & 7) + ((wr_ & 8) ? half : 0); } \
        AP = A + (size_t)grow_*lda + kq_*8; \
        if constexpr (PRODS == 3) ALP = Al + (size_t)grow_*lda + kq_*8; }
#define BINIT(II, LI, OK, PH, PL) { \
        int s_ = tid + (II)*256; int row_ = s_ >> 3, kq_ = s_ & 7; \
        LI = row_*64 + ((kq_*8) ^ ((row_ & 7) << 3)); \
        OK = (c0 + row_ < Cout); \
        int rc_ = OK ? (c0 + row_) : 0; \
        PH = Bh + (size_t)rc_*ldb + kq_*8; \
        PL = Bl + (size_t)rc_*ldb + kq_*8; }
    int ai0, ai1, ai2 = 0, ai3 = 0;
    const ushort_t *ap0, *ap1, *ap2 = nullptr, *ap3 = nullptr;
    const ushort_t *alp0 = nullptr, *alp1 = nullptr;
    AINIT(0, ai0, ap0, alp0);
    AINIT(1, ai1, ap1, alp1);
    if constexpr (NA == 4) {
        AINIT(2, ai2, ap2, alp0);   // PRODS==3 never has NA==4 in this model
        AINIT(3, ai3, ap3, alp0);
        AINIT(0, ai0, ap0, alp0);   // restore (compile-time folded, harmless)
    }
    int bi0, bi1; bool bk0, bk1;
    const ushort_t *bp0h, *bp0l, *bp1h, *bp1l;
    BINIT(0, bi0, bk0, bp0h, bp0l);
    BINIT(1, bi1, bk1, bp1h, bp1l);
#undef AINIT
#undef BINIT
    const uint4 Z4 = make_uint4(0,0,0,0);
    uint4 ra0 = Z4, ra1 = Z4, ra2 = Z4, ra3 = Z4;
    uint4 rl0 = Z4, rl1 = Z4;
    uint4 rb0h = Z4, rb0l = Z4, rb1h = Z4, rb1l = Z4;
#define LOADK(K0V) { \
        ra0 = *(const uint4*)(ap0 + (K0V)); \
        ra1 = *(const uint4*)(ap1 + (K0V)); \
        if constexpr (NA == 4) { \
            ra2 = *(const uint4*)(ap2 + (K0V)); \
            ra3 = *(const uint4*)(ap3 + (K0V)); \
        } \
        if constexpr (PRODS == 3) { \
            rl0 = *(const uint4*)(alp0 + (K0V)); \
            rl1 = *(const uint4*)(alp1 + (K0V)); \
        } \
        rb0h = bk0 ? *(const uint4*)(bp0h + (K0V)) : Z4; \
        rb0l = bk0 ? *(const uint4*)(bp0l + (K0V)) : Z4; \
        rb1h = bk1 ? *(const uint4*)(bp1h + (K0V)) : Z4; \
        rb1l = bk1 ? *(const uint4*)(bp1l + (K0V)) : Z4; }

    const int kchu = (EPI == 8) ? (K / extra_shift) : 0;
    const int kbeg = (EPI == 7) ? by * half : ((EPI == 8) ? kc * kchu : 0);
    const int kend = (EPI == 7) ? kbeg + half : ((EPI == 8) ? kbeg + kchu : K);
    LOADK(kbeg);
    for (int k0 = kbeg; k0 < kend; k0 += 64) {
        __syncthreads();
        *(uint4*)&As[ai0] = ra0;
        *(uint4*)&As[ai1] = ra1;
        if constexpr (NA == 4) {
            *(uint4*)&As[ai2] = ra2;
            *(uint4*)&As[ai3] = ra3;
        }
        if constexpr (PRODS == 3) {
            *(uint4*)&Als[ai0] = rl0;
            *(uint4*)&Als[ai1] = rl1;
        }
        *(uint4*)&Bhs[bi0] = rb0h;
        *(uint4*)&Bhs[bi1] = rb1h;
        *(uint4*)&Bls[bi0] = rb0l;
        *(uint4*)&Bls[bi1] = rb1l;
        if (k0 + 64 < kend) LOADK(k0 + 64);   // prefetch next k-step under this step's MFMA
        __syncthreads();
#pragma unroll
        for (int kc2 = 0; kc2 < 2; kc2++) {
            const int kb = (kc2*32 + lkg*8) ^ sw;
            short8 af[4], bhf[JF], blf[JF];
#pragma unroll
            for (int tI = 0; tI < 4; tI++)
                af[tI]  = *(const short8*)&As [(wm*64 + tI*16 + lrow)*64 + kb];
#pragma unroll
            for (int tJ = 0; tJ < JF; tJ++) {
                bhf[tJ] = *(const short8*)&Bhs[(wn*BANDN + tJ*16 + lrow)*64 + kb];
                blf[tJ] = *(const short8*)&Bls[(wn*BANDN + tJ*16 + lrow)*64 + kb];
            }
#pragma unroll
            for (int i = 0; i < 4; i++)
#pragma unroll
                for (int j = 0; j < JF; j++)
                    acc[i][j] = __builtin_amdgcn_mfma_f32_16x16x32_bf16(af[i], bhf[j], acc[i][j], 0, 0, 0);
#pragma unroll
            for (int i = 0; i < 4; i++)
#pragma unroll
                for (int j = 0; j < JF; j++)
                    acc[i][j] = __builtin_amdgcn_mfma_f32_16x16x32_bf16(af[i], blf[j], acc[i][j], 0, 0, 0);
            if constexpr (PRODS == 3) {
                short8 alf[4];
#pragma unroll
                for (int tI = 0; tI < 4; tI++)
                    alf[tI] = *(const short8*)&Als[(wm*64 + tI*16 + lrow)*64 + kb];
#pragma unroll
                for (int i = 0; i < 4; i++)
#pragma unroll
                    for (int j = 0; j < JF; j++)
                        acc[i][j] = __builtin_amdgcn_mfma_f32_16x16x32_bf16(alf[i], bhf[j], acc[i][j], 0, 0, 0);
            }
        }
    }
#undef LOADK

    const float rbn = 1.0f / sqrtf(1.0f + 1e-5f);
    const int ocol0 = c0 + wn*BANDN + lrow;
    auto spike_pair = [&](float vt) -> ushort_t {
        float vp = __shfl_xor(vt, 32);
        float x0 = (lane < 32) ? vt : vp;
        float x1 = (lane < 32) ? vp : vt;
        float u  = x0 * 0.5f;
        float s0 = (u >= 0.5f) ? 1.f : 0.f;
        u = (s0 > 0.f) ? 0.f : u;
        float u2 = u + (x1 - u) * 0.5f;
        return (lane < 32) ? ((s0 > 0.f) ? BF1 : 0) : ((u2 >= 0.5f) ? BF1 : 0);
    };

    if constexpr (EPI == 0) {
#pragma unroll
        for (int j = 0; j < JF; j++) {
            int col = ocol0 + j*16;
            if (col >= Cout) continue;
            float bsc = 1.f, bsh = 0.f, bv = 0.f;
            if (bng)  { bsc = bng[col] * rbn; bsh = bnb[col]; }
            if (bias) bv = bias[col];
#pragma unroll
            for (int i = 0; i < 4; i++)
#pragma unroll
                for (int r = 0; r < 4; r++) {
                    int grow = r0 + wm*64 + i*16 + lkg*4 + r;
                    float v = acc[i][j][r];
                    if (extra) v += extra[(size_t)(grow >> extra_shift)*Cout + col];
                    v += bv;
                    if (bng) v = v*bsc + bsh;
                    out[(size_t)grow*ldo + col] = v;
                }
        }
    }

    if constexpr (EPI == 7) {
        float* op = out + (size_t)by * rows * ldo;
#pragma unroll
        for (int j = 0; j < JF; j++) {
            int col = ocol0 + j*16;
            if (col >= Cout) continue;
#pragma unroll
            for (int i = 0; i < 4; i++)
#pragma unroll
                for (int r = 0; r < 4; r++) {
                    int grow = r0 + wm*64 + i*16 + lkg*4 + r;
                    op[(size_t)grow*ldo + col] = acc[i][j][r];
                }
        }
    }

    if constexpr (EPI == 8) {
        // row-pair split-K partial store
        float* op = out + (size_t)kc * rows * ldo;
#pragma unroll
        for (int j = 0; j < JF; j++) {
            int col = ocol0 + j*16;
#pragma unroll
            for (int i = 0; i < 4; i++)
#pragma unroll
                for (int r = 0; r < 4; r++) {
                    int orow_t = wm*64 + i*16 + lkg*4 + r;
                    int q = orow_t >> 4, wr = orow_t & 15;
                    int grow = r0h + q*8 + (wr & 7) + ((wr & 8) ? half : 0);
                    op[(size_t)grow*ldo + col] = acc[i][j][r];
                }
        }
    }

    if constexpr (EPI == 6) {
        // enc4: bn + fused max-over-32-rows -> tokens (half = group shift, ldo = DM)
#pragma unroll
        for (int j = 0; j < JF; j++) {
            int col = ocol0 + j*16;
            float bsc = bng[col] * rbn, bsh = bnb[col], bv = bias[col];
            float m0 = -3.0e38f, m1 = -3.0e38f;
#pragma unroll
            for (int i = 0; i < 4; i++)
#pragma unroll
                for (int r = 0; r < 4; r++) {
                    float v = (acc[i][j][r] + bv) * bsc + bsh;
                    if (i < 2) m0 = fmaxf(m0, v); else m1 = fmaxf(m1, v);
                }
            m0 = fmaxf(m0, __shfl_xor(m0, 16)); m0 = fmaxf(m0, __shfl_xor(m0, 32));
            m1 = fmaxf(m1, __shfl_xor(m1, 16)); m1 = fmaxf(m1, __shfl_xor(m1, 32));
            int bg = (r0 >> 5) + wm*2;
            int msk = (1 << half) - 1;
            if (lkg == 0)
                out[(size_t)(bg >> half)*(G_*DM) + (size_t)(bg & msk)*ldo + col] = m0;
            else if (lkg == 1)
                out[(size_t)((bg+1) >> half)*(G_*DM) + (size_t)((bg+1) & msk)*ldo + col] = m1;
        }
    }

    if constexpr (EPI == 5) {
        // group max + LIF -> gls ((ushort*)out), from regs
#pragma unroll
        for (int j = 0; j < JF; j++) {
            int col = ocol0 + j*16;
            float bsc = bng[col] * rbn, bsh = bnb[col], bv = bias[col];
            float gm = -3.0e38f;
#pragma unroll
            for (int i = 0; i < 4; i++)
#pragma unroll
                for (int r = 0; r < 4; r++) {
                    float v = (acc[i][j][r] + bv) * bsc + bsh;
                    gm = fmaxf(gm, v);
                }
            float g2 = fmaxf(gm, __shfl_xor(gm, 16));
            ushort_t gsp = spike_pair(g2);
            ushort_t* gout = (ushort_t*)out;
            int bg = (r0h >> 5) + wm;
            int prs = half >> 5;
            if (lane < 16) gout[(size_t)bg * 256 + col] = gsp;
            else if (lane >= 32 && lane < 48) gout[(size_t)(prs + bg) * 256 + col] = gsp;
        }
    }

    if constexpr (EPI == 2 || EPI == 5) {
        // NB == 64: single-phase staging across As+Bhs+Bls = [128][64] f32
        __syncthreads();
        float* Ef = (float*)As;
#pragma unroll
        for (int j = 0; j < JF; j++) {
            int col = ocol0 + j*16;
            float bsc = 1.f, bsh = 0.f, bv = 0.f;
            if (bng) { bsc = bng[col] * rbn; bsh = bnb[col]; }
            if (bias) bv = bias[col];
#pragma unroll
            for (int i = 0; i < 4; i++)
#pragma unroll
                for (int r = 0; r < 4; r++) {
                    int o = wm*64 + i*16 + lkg*4 + r;
                    int pr = ((o >> 4) << 3) + (o & 7);
                    int tt = (o >> 3) & 1;
                    float v = acc[i][j][r];
                    if (EPI == 2 && extra) {
                        int grw = r0h + pr + (tt ? half : 0);
                        v += extra[(size_t)(grw >> extra_shift)*Cout + col];
                    }
                    v += bv;
                    if (bng) v = v*bsc + bsh;
                    int lr = tt*64 + pr;
                    int cc = wn*BANDN + j*16 + lrow;   // [0,64)
                    Ef[lr*64 + (cc ^ (((lr >> 2) & 3) << 4))] = v;
                }
        }
        __syncthreads();
        {
            int pr2 = tid >> 2, cs = tid & 3;
            int sw2 = ((pr2 >> 2) & 3) << 4;
            const float* E0 = Ef + pr2*64;
            const float* E1 = Ef + (64 + pr2)*64;
            int colg = c0 + cs*16;
            ushort_t* s0p = sout + (size_t)(r0h + pr2)*ldso + colg;
            ushort_t* s1p = s0p + (size_t)half*ldso;
#pragma unroll
            for (int h = 0; h < 4; h++) {
                int cb2 = (cs*16 + h*4) ^ sw2;
                const float* e0 = E0 + cb2;
                const float* e1 = E1 + cb2;
                unsigned oa, ob, pa, pb;
                LIF2(e0[0], e1[0], e0[1], e1[1], oa, pa);
                LIF2(e0[2], e1[2], e0[3], e1[3], ob, pb);
                *(uint2*)(s0p + h*4) = make_uint2(oa, ob);
                *(uint2*)(s1p + h*4) = make_uint2(pa, pb);
            }
        }
    }

    if constexpr (EPI == 3) {
        if (c0 >= DI) {
            // z-gate spikes: direct scatter (32B chunks per 16-lane group)
#pragma unroll
            for (int j = 0; j < JF; j++) {
                int col = ocol0 + j*16;
#pragma unroll
                for (int i = 0; i < 4; i++)
#pragma unroll
                    for (int r = 0; r < 4; r++) {
                        int orow_t = wm*64 + i*16 + lkg*4 + r;
                        int q = orow_t >> 4, wr = orow_t & 15;
                        int grow = r0h + q*8 + (wr & 7) + ((wr & 8) ? half : 0);
                        sout[(size_t)grow*ldso + col - DI] = spike_pair(acc[i][j][r]);
                    }
            }
        } else {
            // ---- fused depthwise conv (causal, DCONV=4) + LIF over staged accumulators ----
            __syncthreads();
            constexpr int GRP = 256 / NB;        // thread groups over l
            constexpr int LPT = 64 / GRP;        // l per thread
            constexpr int SWM = 3;
            float* Sme = wm ? (float*)Bls : (float*)Bhs;   // [32][NB] f32 each
            ushort_t* Asu = As;                  // [64][NB] spike staging (swizzled)
            if (lkg < 2) {                        // t0 rows
#pragma unroll
                for (int j = 0; j < JF; j++) {
                    int dloc = wn*BANDN + j*16 + lrow;
#pragma unroll
                    for (int i = 0; i < 4; i++) {
                        int lr0 = i*8 + lkg*4;
#pragma unroll
                        for (int r = 0; r < 4; r++)
                            Sme[(lr0 + r)*NB + dloc] = acc[i][j][r];
                    }
                }
            }
            __syncthreads();
            const int dloc_c = tid & (NB - 1);
            const int lb = (tid / NB) * LPT;
            const int dg = c0 + dloc_c;
            const float cw0 = extra[dg*4+0], cw1 = extra[dg*4+1];
            const float cw2 = extra[dg*4+2], cw3 = extra[dg*4+3];
            const float cbv = bias[dg];
            const float* S0f = (const float*)Bhs;
            const float* S1f = (const float*)Bls;
            auto SRD = [&](int l) -> float {
                return (l < 32) ? S0f[l*NB + dloc_c] : S1f[(l - 32)*NB + dloc_c];
            };
            float a0[LPT];                        // reset potential after t0
            {
                float vm3 = 0.f, vm2 = 0.f, vm1 = 0.f;
                if (lb) { vm3 = SRD(lb-3); vm2 = SRD(lb-2); vm1 = SRD(lb-1); }
#pragma unroll
                for (int q = 0; q < LPT; q++) {
                    float v = SRD(lb + q);
                    float aa = vm3*cw0 + vm2*cw1 + vm1*cw2 + v*cw3 + cbv;
                    vm3 = vm2; vm2 = vm1; vm1 = v;
                    float u = aa * 0.5f;
                    float sv = (u >= 0.5f) ? 1.f : 0.f;
                    a0[q] = (sv > 0.f) ? 0.f : u;
                    int l = lb + q;
                    Asu[l*NB + (dloc_c ^ (((l >> 1) & SWM) << 4))] = (sv > 0.f) ? BF1 : 0;
                }
            }
            __syncthreads();
            if (lkg >= 2) {                       // t1 rows
#pragma unroll
                for (int j = 0; j < JF; j++) {
                    int dloc = wn*BANDN + j*16 + lrow;
#pragma unroll
                    for (int i = 0; i < 4; i++) {
                        int lr0 = i*8 + (lkg - 2)*4;
#pragma unroll
                        for (int r = 0; r < 4; r++)
                            Sme[(lr0 + r)*NB + dloc] = acc[i][j][r];
                    }
                }
            }
            // t0 spike tile write-out (disjoint LDS from t1 staging)
            ushort_t* xb0 = (ushort_t*)out + (size_t)bx * G_ * DI + c0;
            constexpr int CPT = NB / 4;           // shorts per thread per row
            {
                int row = tid >> 2, cs2 = tid & 3;
                int sw2 = ((row >> 1) & SWM) << 4;
                ushort_t* xrow = xb0 + (size_t)row * DI;
#pragma unroll
                for (int kk = 0; kk < NB/64; kk++) {
                    int cb2 = cs2*CPT + kk*16;
                    int cl = cb2 ^ sw2;
                    uint4 va = *(uint4*)&Asu[row*NB + cl];
                    uint4 vb = *(uint4*)&Asu[row*NB + cl + 8];
                    *(uint4*)&xrow[cb2] = va;
                    *(uint4*)&xrow[cb2 + 8] = vb;
                }
            }
            __syncthreads();
            {
                float vm3 = 0.f, vm2 = 0.f, vm1 = 0.f;
                if (lb) { vm3 = SRD(lb-3); vm2 = SRD(lb-2); vm1 = SRD(lb-1); }
#pragma unroll
                for (int q = 0; q < LPT; q++) {
                    float v = SRD(lb + q);
                    float a1 = vm3*cw0 + vm2*cw1 + vm1*cw2 + v*cw3 + cbv;
                    vm3 = vm2; vm2 = vm1; vm1 = v;
                    float u2 = a0[q] + (a1 - a0[q]) * 0.5f;
                    int l = lb + q;
                    Asu[l*NB + (dloc_c ^ (((l >> 1) & SWM) << 4))] = (u2 >= 0.5f) ? BF1 : 0;
                }
            }
            __syncthreads();
            {
                int row = tid >> 2, cs2 = tid & 3;
                int sw2 = ((row >> 1) & SWM) << 4;
                ushort_t* xrow = xb0 + (size_t)16 * G_ * DI + (size_t)row * DI;
#pragma unroll
                for (int kk = 0; kk < NB/64; kk++) {
                    int cb2 = cs2*CPT + kk*16;
                    int cl = cb2 ^ sw2;
                    uint4 va = *(uint4*)&Asu[row*NB + cl];
                    uint4 vb = *(uint4*)&Asu[row*NB + cl + 8];
                    *(uint4*)&xrow[cb2] = va;
                    *(uint4*)&xrow[cb2 + 8] = vb;
                }
            }
        }
    }
}

// ---------------- out_proj split-K fixup: sum partials + residual RMW + LIF -> hs ----------------
__global__ __launch_bounds__(256) void opfix_kernel(
    const float* __restrict__ part,      // [OKC][2048][DM]
    float* __restrict__ residual, ushort_t* __restrict__ hs) {
    int e = blockIdx.x * 256 + threadIdx.x;
    if (e >= 1024 * (DM/4)) return;
    int r = e / (DM/4), c4 = (e % (DM/4)) * 4;
    size_t o0 = (size_t)r * DM + c4;
    size_t o1 = (size_t)(r + 1024) * DM + c4;
    float4 s0 = *(const float4*)(part + o0);
    float4 s1 = *(const float4*)(part + o1);
#pragma unroll
    for (int k = 1; k < OKC; k++) {
        float4 p0 = *(const float4*)(part + (size_t)k*2048*DM + o0);
        float4 p1 = *(const float4*)(part + (size_t)k*2048*DM + o1);
        s0.x += p0.x; s0.y += p0.y; s0.z += p0.z; s0.w += p0.w;
        s1.x += p1.x; s1.y += p1.y; s1.z += p1.z; s1.w += p1.w;
    }
    float4 rv0 = *(float4*)(residual + o0);
    float4 rv1 = *(float4*)(residual + o1);
    float t0x = s0.x+rv0.x, t0y = s0.y+rv0.y, t0z = s0.z+rv0.z, t0w = s0.w+rv0.w;
    float t1x = s1.x+rv1.x, t1y = s1.y+rv1.y, t1z = s1.z+rv1.z, t1w = s1.w+rv1.w;
    *(float4*)(residual + o0) = make_float4(t0x, t0y, t0z, t0w);
    *(float4*)(residual + o1) = make_float4(t1x, t1y, t1z, t1w);
    unsigned oa, ob, pa, pb;
    LIF2(t0x, t1x, t0y, t1y, oa, pa);
    LIF2(t0z, t1z, t0w, t1w, ob, pb);
    *(uint2*)(hs + o0) = make_uint2(oa, ob);
    *(uint2*)(hs + o1) = make_uint2(pa, pb);
}

// ---------------- f32 register-tiled GEMM (pos2 only) ----------------
#define KT 32
#define FMA_ROW(accv, s) { accv.x += b.x*(s); accv.y += b.y*(s); accv.z += b.z*(s); accv.w += b.w*(s); }
template<int RPT>
__global__ __launch_bounds__(256) void gemm_kernel(
    const float* __restrict__ A, int lda,
    const float* __restrict__ Wt, int ldw,
    const float* __restrict__ bias,
    float* __restrict__ out, int ldo,
    int rows, int K, int Cout, int act)
{
    constexpr int BM = RPT * 16;
    __shared__ __align__(16) float As[KT][BM];
    __shared__ __align__(16) float Bs[KT][64];
    const int tid = threadIdx.x;
    const int r0 = blockIdx.x * BM;
    const int c0 = blockIdx.y * 64;
    const int tx = tid & 15, ty = tid >> 4;
    const int colb = c0 + tx * 4;
    const float4 z4 = make_float4(0.f, 0.f, 0.f, 0.f);
    float4 acc0 = z4, acc1 = z4, acc2 = z4, acc3 = z4;
    for (int k0 = 0; k0 < K; k0 += KT) {
        for (int s = tid; s < BM * 8; s += 256) {
            int row = s >> 3, kq = s & 7;
            int dcol = row ^ (kq << 2);
            float4 va = z4;
            if (r0 + row < rows && (k0 + kq*4) < K)
                va = *(const float4*)(A + (size_t)(r0+row)*lda + k0 + kq*4);
            As[kq*4+0][dcol] = va.x; As[kq*4+1][dcol] = va.y;
            As[kq*4+2][dcol] = va.z; As[kq*4+3][dcol] = va.w;
        }
        for (int s = tid; s < 512; s += 256) {
            int row = s >> 3, kq = s & 7;
            int dcol = row ^ (kq << 2);
            float4 vb = z4;
            if (c0 + row < Cout && (k0 + kq*4) < K)
                vb = *(const float4*)(Wt + (size_t)(c0+row)*ldw + k0 + kq*4);
            Bs[kq*4+0][dcol] = vb.x; Bs[kq*4+1][dcol] = vb.y;
            Bs[kq*4+2][dcol] = vb.z; Bs[kq*4+3][dcol] = vb.w;
        }
        __syncthreads();
#pragma unroll 4
        for (int k = 0; k < KT; k++) {
            const int swz = ((k >> 2) & 7) << 2;
            const float4 b  = *(const float4*)&Bs[k][(tx*4) ^ swz];
            const float4 a0 = *(const float4*)&As[k][(ty*RPT) ^ swz];
            FMA_ROW(acc0, a0.x); FMA_ROW(acc1, a0.y);
            FMA_ROW(acc2, a0.z); FMA_ROW(acc3, a0.w);
        }
        __syncthreads();
    }
    if (colb >= Cout) return;
    float4 o4 = z4;
    if (bias) { o4.x = bias[colb]; o4.y = bias[colb+1]; o4.z = bias[colb+2]; o4.w = bias[colb+3]; }
    const int rbase = r0 + ty * RPT;
#define EPILOG(accv, rr) { \
    int row = rbase + (rr); \
    if (row < rows) { \
        float4 v = accv; \
        v.x += o4.x; v.y += o4.y; v.z += o4.z; v.w += o4.w; \
        *(float4*)(out + (size_t)row*ldo + colb) = v; \
    } }
    EPILOG(acc0, 0); EPILOG(acc1, 1); EPILOG(acc2, 2); EPILOG(acc3, 3);
#undef EPILOG
}

// ---------------- pos1 skinny matmul (K=3) + gelu ----------------
#define MMR 16
__global__ __launch_bounds__(256) void mm_kernel(
    const float* __restrict__ in, const float* __restrict__ Wt,
    const float* __restrict__ bias, float* __restrict__ out,
    int rows, int Cout, int act) {
    __shared__ __align__(16) float lds[MMR * 4];
    int tid = threadIdx.x;
    int r0  = blockIdx.x * MMR;
    int o   = tid & 127;
    for (int i = tid; i < MMR * 4; i += 256) {
        int rr = i >> 2, cc = i & 3;
        int row = r0 + rr;
        lds[i] = (row < rows && cc < 3) ? in[(size_t)row*3 + cc] : 0.f;
    }
    __syncthreads();
    if (tid >= 128 || o >= Cout) return;
    float w0 = Wt[o*3], w1 = Wt[o*3+1], w2 = Wt[o*3+2];
    float bv = bias ? bias[o] : 0.f;
    for (int r = 0; r < MMR; r++) {
        int row = r0 + r;
        if (row >= rows) break;
        float v = lds[r*4]*w0 + lds[r*4+1]*w1 + lds[r*4+2]*w2 + bv;
        if (act == 1) {
            float u = 0.7978845608028654f * (v + 0.044715f * v * v * v);
            v = 0.5f * v * (1.f + tanhf(u));
        }
        out[(size_t)row * 128 + o] = v;
    }
}

// ---------------- enc1 (K=3) + bn + LIF -> bf16 spikes ----------------
__global__ __launch_bounds__(256) void enc1_lif_kernel(
    const float* __restrict__ nb, const float* __restrict__ w, const float* __restrict__ bias,
    const float* __restrict__ bng, const float* __restrict__ bnb,
    ushort_t* __restrict__ f1s, int g0, int half, int bgsh) {
    int e = blockIdx.x * 256 + threadIdx.x;
    if (e >= half * 128) return;
    int r = e >> 7, col = e & 127;
    int tb = r >> bgsh, rem = r & ((1 << bgsh) - 1);
    int gl = rem >> 5, m = rem & 31;
    size_t i0 = (((size_t)tb * G_ + g0 + gl) * M_ + m) * 3;
    size_t i1 = i0 + (size_t)16 * G_ * M_ * 3;
    float w0 = w[col*3], w1 = w[col*3+1], w2 = w[col*3+2];
    float sc = bng[col] / sqrtf(1.f + 1e-5f), sh = bnb[col], bv = bias[col];
    float a0 = (nb[i0]*w0 + nb[i0+1]*w1 + nb[i0+2]*w2 + bv) * sc + sh;
    float a1 = (nb[i1]*w0 + nb[i1+1]*w1 + nb[i1+2]*w2 + bv) * sc + sh;
    float u  = a0 * 0.5f;
    float s0 = (u >= 0.5f) ? 1.f : 0.f;
    u = (s0 > 0.f) ? 0.f : u;
    float u2 = u + (a1 - u) * 0.5f;
    f1s[(size_t)r * 128 + col] = (s0 > 0.f) ? BF1 : 0;
    f1s[((size_t)half + r) * 128 + col] = (u2 >= 0.5f) ? BF1 : 0;
}

// ---------------- addpos + LIF -> residual f32 + hs spikes ----------------
__global__ __launch_bounds__(256) void addpos_lif_kernel(
    const float* __restrict__ tokens, const float* __restrict__ pos,
    float* __restrict__ residual, ushort_t* __restrict__ hs, int half) {
    int e = blockIdx.x * 256 + threadIdx.x;
    if (e >= half) return;
    float p = pos[e];
    float r0 = tokens[e] + p;
    float r1 = tokens[e + half] + p;
    residual[e] = r0; residual[e + half] = r1;
    float v  = r0 * 0.5f;
    float s0 = (v >= 0.5f) ? 1.f : 0.f;
    v = (s0 > 0.f) ? 0.f : v;
    float v2 = v + (r1 - v) * 0.5f;
    hs[e] = (s0 > 0.f) ? BF1 : 0;
    hs[e + half] = (v2 >= 0.5f) ? BF1 : 0;
}

// ---------------- selective scan: 4 states/lane, 64 d/block, zero global ops in loop ----------------
__global__ __launch_bounds__(256) void scan_kernel(
    const float* __restrict__ dbl,
    const ushort_t* __restrict__ xs, const ushort_t* __restrict__ zs,
    const float* __restrict__ A_log, const float* __restrict__ Dp,
    const float* __restrict__ dt_w, const float* __restrict__ dt_b,
    ushort_t* __restrict__ yh, ushort_t* __restrict__ yl) {
    int tb = blockIdx.x;
    int d0 = blockIdx.y * 64;
    int tid = threadIdx.x;
    const int dl = tid >> 2;        // local d channel 0..63
    const int sg = tid & 3;         // state group (4 states each)
    const int d  = d0 + dl;
    __shared__ float SD[G_][56];    // [dt_in(24) | B(16) | C(16)] rows
    __shared__ float SDT[G_][64];   // softplus(dt) per (l, d_local)
    __shared__ ushort_t SX[G_][64]; // xs tile
    __shared__ ushort_t SZ[G_][64]; // zs tile
    __shared__ ushort_t SYH[G_][64];// yh out tile
    __shared__ ushort_t SYL[G_][64];// yl out tile
    for (int i = tid; i < G_ * 56; i += 256) {
        int l = i / 56, j = i - l * 56;
        const float* dp0 = dbl + ((size_t)tb * G_ + l) * 56 + j;
        float sv = 0.f;
#pragma unroll
        for (int p = 0; p < KSPL; p++) sv += dp0[(size_t)p * TB * G_ * 56];
        SD[l][j] = sv;
    }
    for (int i = tid; i < G_ * 8; i += 256) {
        int row = i >> 3, seg = i & 7;
        size_t go = ((size_t)tb * G_ + row) * DI + d0 + seg*8;
        *(uint4*)&SX[row][seg*8] = *(const uint4*)(xs + go);
        *(uint4*)&SZ[row][seg*8] = *(const uint4*)(zs + go);
    }
    __syncthreads();
    {
        int dloc = tid & 63;
        int dd = d0 + dloc;
        float wdt[DTR];
#pragma unroll
        for (int k = 0; k < DTR; k++) wdt[k] = dt_w[dd * DTR + k];
        float db = dt_b[dd];
        int lbase = tid >> 6;
#pragma unroll
        for (int st = 0; st < 16; st++) {
            int l = lbase + st * 4;
            float dtv = db;
#pragma unroll
            for (int k = 0; k < DTR; k++) dtv += SD[l][k] * wdt[k];
            dtv = fmaxf(dtv, 0.f) + log1pf(EXP2F(-fabsf(dtv) * LOG2E));
            SDT[l][dloc] = dtv;
        }
    }
    __syncthreads();
    float A2[4];
#pragma unroll
    for (int k = 0; k < 4; k++)
        A2[k] = -EXP2F(A_log[d * DS + 4*sg + k] * LOG2E) * LOG2E;
    const float dpv = Dp[d];
    float h0 = 0.f, h1 = 0.f, h2 = 0.f, h3 = 0.f;
#pragma unroll 4
    for (int l = 0; l < G_; l++) {
        float dtv = SDT[l][dl];
        float4 Bv = *(const float4*)&SD[l][DTR + 4*sg];
        float4 Cv = *(const float4*)&SD[l][DTR + DS + 4*sg];
        float xv = b2f(SX[l][dl]);
        float dx = dtv * xv;
        h0 = h0 * EXP2F(dtv * A2[0]) + dx * Bv.x;
        h1 = h1 * EXP2F(dtv * A2[1]) + dx * Bv.y;
        h2 = h2 * EXP2F(dtv * A2[2]) + dx * Bv.z;
        h3 = h3 * EXP2F(dtv * A2[3]) + dx * Bv.w;
        float p = h0*Cv.x + h1*Cv.y + h2*Cv.z + h3*Cv.w;
        DPP_FADD(p, 0xB1);          // += lane^1 (quad_perm, VALU)
        DPP_FADD(p, 0x4E);          // += lane^2
        if (sg == 0) {
            float y = (p + xv * dpv) * b2f(SZ[l][dl]);
            ushort_t hb = f2b(y);
            SYH[l][dl] = hb;
            SYL[l][dl] = f2b(y - b2f(hb));
        }
    }
    __syncthreads();
    for (int i = tid; i < G_ * 8; i += 256) {
        int row = i >> 3, seg = i & 7;
        size_t go = ((size_t)tb * G_ + row) * DI + d0 + seg*8;
        *(uint4*)(yh + go) = *(uint4*)&SYH[row][seg*8];
        *(uint4*)(yl + go) = *(uint4*)&SYL[row][seg*8];
    }
}

// ---------------- final LayerNorm (single input) ----------------
__global__ __launch_bounds__(128) void ln_kernel(const float* __restrict__ in1,
                                                 const float* __restrict__ g,
                                                 const float* __restrict__ b,
                                                 float* __restrict__ out) {
    int row = blockIdx.x;
    __shared__ float xsm[DM];
    __shared__ float red[128];
    int tid = threadIdx.x;
    float s = 0.f;
    for (int c = tid; c < DM; c += 128) {
        float x = in1[(size_t)row * DM + c];
        xsm[c] = x; s += x;
    }
    red[tid] = s; __syncthreads();
    for (int w = 64; w > 0; w >>= 1) { if (tid < w) red[tid] += red[tid + w]; __syncthreads(); }
    float mu = red[0] / DM;
    __syncthreads();
    float s2 = 0.f;
    for (int c = tid; c < DM; c += 128) { float dv = xsm[c] - mu; s2 += dv * dv; }
    red[tid] = s2; __syncthreads();
    for (int w = 64; w > 0; w >>= 1) { if (tid < w) red[tid] += red[tid + w]; __syncthreads(); }
    float var = red[0] / DM;
    float inv = 1.f / sqrtf(var + 1e-5f);
    for (int c = tid; c < DM; c += 128)
        out[(size_t)row * DM + c] = (xsm[c] - mu) * inv * g[c] + b[c];
}

// ---------------- host orchestration ----------------
extern "C" void kernel_launch(void* const* d_in, const int* in_sizes, int n_in,
                              void* d_out, int out_size, void* d_ws, size_t ws_size,
                              hipStream_t stream) {
    const float* xyz     = (const float*)d_in[0];
    const float* enc1_w  = (const float*)d_in[1];  const float* enc1_b = (const float*)d_in[2];
    const float* bn1_g   = (const float*)d_in[3];  const float* bn1_b  = (const float*)d_in[4];
    const float* enc2_w  = (const float*)d_in[5];  const float* enc2_b = (const float*)d_in[6];
    const float* bn2_g   = (const float*)d_in[7];  const float* bn2_b  = (const float*)d_in[8];
    const float* enc3_w  = (const float*)d_in[9];  const float* enc3_b = (const float*)d_in[10];
    const float* bn3_g   = (const float*)d_in[11]; const float* bn3_b  = (const float*)d_in[12];
    const float* enc4_w  = (const float*)d_in[13]; const float* enc4_b = (const float*)d_in[14];
    const float* bn4_g   = (const float*)d_in[15]; const float* bn4_b  = (const float*)d_in[16];
    const float* pos1_w  = (const float*)d_in[17]; const float* pos1_b = (const float*)d_in[18];
    const float* pos2_w  = (const float*)d_in[19]; const float* pos2_b = (const float*)d_in[20];
    const float* in_w    = (const float*)d_in[21];
    const float* conv_w  = (const float*)d_in[22]; const float* conv_b = (const float*)d_in[23];
    const float* xproj_w = (const float*)d_in[24];
    const float* dt_w    = (const float*)d_in[25]; const float* dt_b   = (const float*)d_in[26];
    const float* A_log   = (const float*)d_in[27]; const float* Dp     = (const float*)d_in[28];
    const float* out_w   = (const float*)d_in[29];
    const float* normf_g = (const float*)d_in[30]; const float* normf_b = (const float*)d_in[31];
    float* outp = (float*)d_out;
    float* ws   = (float*)d_ws;
    const size_t wf = ws_size / 4;

    // ---- plan selection: widest encoder chunk that fits ----
    const size_t NIW = 12*589824, NXP = 12*43008, NOW = 12*294912;
    auto pool_need = [&](int g) -> size_t {
        size_t R = (size_t)g*1024, CBx = (size_t)g*32;
        return R*1088 + CBx*640;
    };
    const size_t fixed_need = 4200000;
    int gch = 8; bool split_all = false;
    {
        const int cand[4] = {64, 32, 16, 8};
        for (int ci = 0; ci < 4; ci++) {
            if (fixed_need + (NIW+NXP+NOW) + pool_need(cand[ci]) <= wf) {
                gch = cand[ci]; split_all = true; break;
            }
        }
    }
    auto ilog2i = [](int x){ int r = 0; while ((1 << r) < x) r++; return r; };
    const int R = gch*1024, HALF = R/2, CB = gch*32;
    const int NCH = 64/gch;
    const int BGSH = 5 + ilog2i(gch);
    const int OGSH = ilog2i(gch);

    size_t off = 0;
    auto alloc = [&](size_t n) { off = (off + 15) & ~(size_t)15; float* p = ws + off; off += n; return p; };
    float* centers  = alloc(3072);
    float* nb       = alloc(196608);
    float* tokens   = alloc(786432);
    float* post     = alloc(131072);
    float* pos      = alloc(393216);
    float* residual = alloc(786432);
    ushort_t* hs_b  = (ushort_t*)alloc(393216);
    ushort_t* ewhi  = (ushort_t*)alloc(245760);
    ushort_t* ewlo  = (ushort_t*)alloc(245760);
    size_t wsz = split_all ? (NIW+NXP+NOW) : 927744;
    ushort_t* whi = (ushort_t*)alloc((wsz+1)/2);
    ushort_t* wlo = (ushort_t*)alloc((wsz+1)/2);
    float* pool = alloc(pool_need(gch));
    // encoder aliases
    float* f2 = pool;
    float* f4 = f2 + (size_t)R*256;
    float* g3 = f4 + (size_t)R*384;
    ushort_t* f1s = (ushort_t*)(g3 + (size_t)CB*512);
    ushort_t* f2s = f1s + (size_t)R*128;
    ushort_t* f3s = f2s + (size_t)R*256;
    ushort_t* gls = f3s + (size_t)R*512;
    // mamba aliases (encoder done before use); dblb holds KSPL split-K partials
    float* dblb  = pool;                                   // KSPL * 2048 * 56
    ushort_t* xs_b = (ushort_t*)(dblb + KSPL * TB * G_ * 56);
    ushort_t* zs_b = xs_b + 1572864;
    ushort_t* ysh  = zs_b + 1572864;
    ushort_t* ysl  = ysh + 1572864;
    float* opart   = (float*)(ysl + 1572864);              // OKC * 2048 * DM f32

    // weight splits
    wsplit3_kernel<<<512, 256, 0, stream>>>(enc2_w, 32768, enc3_w, 262144, enc4_w, 196608, ewhi, ewlo);
    const int E2 = 0, E3 = 32768, E4 = 294912;
    if (split_all)
        wsplit3_kernel<<<2048, 256, 0, stream>>>(in_w, (int)NIW, xproj_w, (int)NXP, out_w, (int)NOW, whi, wlo);

    fps_kernel<<<B_, 64, 0, stream>>>(xyz, centers);
    knn_kernel<<<TB * 16, 256, 0, stream>>>(xyz, centers, nb);

    // ---- encoder ----
    for (int ch = 0; ch < NCH; ch++) {
        int g0 = ch * gch;
        enc1_lif_kernel<<<(HALF*128 + 255)/256, 256, 0, stream>>>(
            nb, enc1_w, enc1_b, bn1_g, bn1_b, f1s, g0, HALF, BGSH);
        // enc2 + bn + staged spikes + fused max-over-M + LIF -> gls
        gemm_mfma<2,5,128,64><<<dim3(HALF/64, 4), 256, 0, stream>>>(
            f1s, nullptr, 128, ewhi + E2, ewlo + E2, 128,
            enc2_b, bn2_g, bn2_b, nullptr, 0, (float*)gls, 0, f2s, 256, HALF, R, 128, 256);
        gemm_mfma<2,0,64,64><<<dim3(CB/64, 8), 256, 0, stream>>>(
            gls, nullptr, 256, ewhi + E3, ewlo + E3, 512,
            nullptr, nullptr, nullptr, nullptr, 0, g3, 512, nullptr, 0, 0, CB, 256, 512);
        gemm_mfma<2,2,128,64><<<dim3(HALF/64, 8), 256, 0, stream>>>(
            f2s, nullptr, 256, ewhi + E3 + 256, ewlo + E3 + 256, 512,
            enc3_b, bn3_g, bn3_b, g3, 5, nullptr, 512, f3s, 512, HALF, R, 256, 512);
        // enc4 + bn + fused max-over-M -> tokens (no f4 round-trip)
        gemm_mfma<2,6,128,64><<<dim3(R/128, 6), 256, 0, stream>>>(
            f3s, nullptr, 512, ewhi + E4, ewlo + E4, 512,
            enc4_b, bn4_g, bn4_b, nullptr, 0,
            tokens + (size_t)g0 * DM, DM, nullptr, 0, OGSH, R, 512, 384);
    }

    // ---- positional embedding (+ layer-0 residual/LIF) ----
    mm_kernel<<<64, 256, 0, stream>>>(centers, pos1_w, pos1_b, post, 1024, 128, 1);
    gemm_kernel<4><<<dim3(16, 6), 256, 0, stream>>>(
        post, 128, pos2_w, 128, pos2_b, pos, 384, 1024, 128, 384, 0);
    addpos_lif_kernel<<<(393216 + 255) / 256, 256, 0, stream>>>(
        tokens, pos, residual, hs_b, 393216);

    // ---- 12 spiking-Mamba layers ----
    const int NTOK = TB * G_;
    for (int l = 0; l < NLAYER; l++) {
        size_t W_IN, W_XP, W_OUT;
        if (split_all) {
            W_IN = (size_t)l * 589824;
            W_XP = NIW + (size_t)l * 43008;
            W_OUT = NIW + NXP + (size_t)l * 294912;
        } else {
            wsplit3_kernel<<<1024, 256, 0, stream>>>(
                in_w + (size_t)l * 589824, 589824,
                xproj_w + (size_t)l * 43008, 43008,
                out_w + (size_t)l * 294912, 294912, whi, wlo);
            W_IN = 0; W_XP = 589824; W_OUT = 632832;
        }
        // in_proj fused with depthwise conv + LIF (xh cols) and z-gate spikes (z cols)
        gemm_mfma<2,3,128,64><<<dim3(NTOK/128, 24), 256, 0, stream>>>(
            hs_b, nullptr, DM, whi + W_IN, wlo + W_IN, DM,
            conv_b + (size_t)l * DI, nullptr, nullptr, conv_w + (size_t)l * DI * DCONV, 0,
            (float*)xs_b, 0, zs_b, DI, NTOK/2, NTOK, DM, 2*DI);
        // xproj: split-K over 6 chunks -> dblb partials (summed inside scan)
        gemm_mfma<2,7,64,64><<<dim3(NTOK/64, KSPL), 256, 0, stream>>>(
            xs_b, nullptr, DI, whi + W_XP, wlo + W_XP, DI,
            nullptr, nullptr, nullptr, nullptr, 0, dblb, 56, nullptr, 0, DI/KSPL, NTOK, DI, 56);
        // scan (fused dt_proj + gate, 4-state lanes, LDS-resident loop) -> ys hi/lo
        scan_kernel<<<dim3(TB, DI/64), 256, 0, stream>>>(
            dblb, xs_b, zs_b, A_log + (size_t)l * DI * DS, Dp + (size_t)l * DI,
            dt_w + (size_t)l * DI * DTR, dt_b + (size_t)l * DI, ysh, ysl);
        // out_proj split-K (4 chunks x 6 col bands) -> opart partials
        gemm_mfma<3,8,64,64><<<dim3(NTOK/64, 6*OKC), 256, 0, stream>>>(
            ysh, ysl, DI, whi + W_OUT, wlo + W_OUT, DI,
            nullptr, nullptr, nullptr, nullptr, OKC, opart, DM, nullptr, 0, NTOK/2, NTOK, DI, DM);
        // fixup: sum partials + residual RMW + next-layer LIF spikes
        opfix_kernel<<<(1024*(DM/4) + 255)/256, 256, 0, stream>>>(opart, residual, hs_b);
    }
    ln_kernel<<<NTOK, 128, 0, stream>>>(residual, normf_g, normf_b, outp);
}